// Round 9
// baseline (250.712 us; speedup 1.0000x reference)
//
#include <hip/hip_runtime.h>
#include <math.h>

#define PI_F 3.14159265358979323846f

// ============ SIFT PS=8 (K=28): one WAVE per patch, no LDS, no barriers ============
// Uniform scale factors (1/gsum^2, pooling 0.25, 1/(HALF*HALF)) are dropped:
// they cancel at the first L2 normalization of the descriptor chain.
__global__ __launch_bounds__(256)
void sift8_wave(const float* __restrict__ x, float* __restrict__ out)
{
    const int tid = threadIdx.x;
    const int l = tid & 63;
    const int wv = tid >> 6;
    const int n = blockIdx.x*4 + wv;      // 12544 patches
    const int b = n / 784;
    const int c = n % 784;
    const int ki = c / 28, kj = c % 28;
    const int i = l >> 3, j = l & 7;

    const float* xb = x + (size_t)b*50176;
    float v = xb[(i*28 + ki)*224 + (j*28 + kj)];

    // spatial gradient (replicate pad) via lane shuffles
    int lL = (j > 0) ? l-1 : l;
    int lR = (j < 7) ? l+1 : l;
    int lU = (i > 0) ? l-8 : l;
    int lD = (i < 7) ? l+8 : l;
    float pL = __shfl(v, lL);
    float pR = __shfl(v, lR);
    float pU = __shfl(v, lU);
    float pD = __shfl(v, lD);
    float gx = 0.5f*(pR - pL);
    float gy = 0.5f*(pD - pU);

    // gaussian weight (unnormalized; sigma = 8/sqrt(2))
    float ti = ((float)i - 3.5f) * (1.f/5.65685424949238f);
    float tj = ((float)j - 3.5f) * (1.f/5.65685424949238f);
    float wsp = __expf(-0.5f*(ti*ti + tj*tj));
    float mag = sqrtf(gx*gx + gy*gy + 1e-10f) * wsp;
    float ori = atan2f(gy, gx + 1e-10f) + 2.f*PI_F;
    float obig = ori * (8.f/(2.f*PI_F));
    float bo0f = floorf(obig);
    float w1 = obig - bo0f;
    int bo0 = ((int)bo0f) & 7;
    int bo1 = (bo0 + 1) & 7;
    float c0 = (1.f - w1)*mag;
    float c1 = w1*mag;

    // 2x2-cell pooling (BK=2, stride=2, pad=0; taps uniform -> dropped):
    // cell mates are lanes l^1 (col pair) and l^8 (row pair).
    const int t = ((i & 1) << 1) | (j & 1);   // sub-position in cell: 0..3
    float d0 = 0.f, d1 = 0.f;
    #pragma unroll
    for (int o = 0; o < 8; o++) {
        float val = (bo0 == o ? c0 : 0.f) + (bo1 == o ? c1 : 0.f);
        val += __shfl_xor(val, 1);
        val += __shfl_xor(val, 8);
        if (o == 2*t)     d0 = val;
        if (o == 2*t + 1) d1 = val;
    }

    // normalize chain: L2 -> clip 0.2 -> L2 -> rootsift (butterfly reduces)
    float s = d0*d0 + d1*d1;
    #pragma unroll
    for (int off = 32; off > 0; off >>= 1) s += __shfl_xor(s, off);
    float nrm = fmaxf(sqrtf(s), 1e-12f);
    d0 /= nrm; d1 /= nrm;
    d0 = fminf(fmaxf(d0, 0.f), 0.2f);
    d1 = fminf(fmaxf(d1, 0.f), 0.2f);
    s = d0*d0 + d1*d1;
    #pragma unroll
    for (int off = 32; off > 0; off >>= 1) s += __shfl_xor(s, off);
    nrm = fmaxf(sqrtf(s), 1e-12f);
    d0 /= nrm; d1 /= nrm;
    s = d0 + d1;    // d >= 0
    #pragma unroll
    for (int off = 32; off > 0; off >>= 1) s += __shfl_xor(s, off);
    s = fmaxf(s, 1e-12f);
    d0 = sqrtf(d0/s + 1e-10f);
    d1 = sqrtf(d1/s + 1e-10f);

    int cell = (i >> 1)*4 + (j >> 1);
    float* ob = out + (size_t)n*128 + cell;
    ob[(2*t)*16]     = d0;
    ob[(2*t + 1)*16] = d1;
}

// ======================= SIFT descriptor (PS=32 / PS=16, LDS version) =======================
template<int PS, int K, int NT>
__global__ __launch_bounds__(NT)
void sift_kernel(const float* __restrict__ x, float* __restrict__ out)
{
    constexpr int NPIX = PS*PS;
    constexpr int BK = 2*(PS/5);
    constexpr int STRIDE = PS/4;
    constexpr int PAD = BK/4;
    constexpr float HALF = BK*0.5f;
    constexpr int NWAVE = NT/64;
    constexpr int HALVES = (NT >= 256) ? 2 : 1;
    constexpr int ROWS = BK / HALVES;

    __shared__ float patch[NPIX];
    __shared__ float bins[8*NPIX];
    __shared__ float g1[PS];
    __shared__ float pool2[128];
    __shared__ float wred[NWAVE];
    __shared__ float gsum_s;

    const int tid = threadIdx.x;
    const int n = blockIdx.x;
    const int b = n / (K*K);
    const int c = n % (K*K);
    const int ki = c / K;
    const int kj = c % K;

    const float* xb = x + (size_t)b*224*224;
    for (int idx = tid; idx < NPIX; idx += NT) {
        int i = idx / PS, j = idx - i*PS;
        patch[idx] = xb[(i*K + ki)*224 + (j*K + kj)];
    }
    if (tid < PS) {
        const float sigma = (float)PS * 0.70710678118654752440f;
        float xv = (float)tid - (PS-1)*0.5f;
        float t = xv / sigma;
        g1[tid] = expf(-0.5f*t*t);
    }
    for (int idx = tid; idx < 8*NPIX; idx += NT) bins[idx] = 0.f;
    __syncthreads();
    if (tid == 0) {
        float s = 0.f;
        for (int i = 0; i < PS; i++) s += g1[i];
        gsum_s = s;
    }
    __syncthreads();
    const float ginv = 1.0f / (gsum_s*gsum_s);

    for (int idx = tid; idx < NPIX; idx += NT) {
        int i = idx / PS, j = idx - i*PS;
        int jm = j > 0 ? j-1 : 0, jp = j < PS-1 ? j+1 : PS-1;
        int im = i > 0 ? i-1 : 0, ip = i < PS-1 ? i+1 : PS-1;
        float gx = 0.5f*(patch[i*PS+jp] - patch[i*PS+jm]);
        float gy = 0.5f*(patch[ip*PS+j] - patch[im*PS+j]);
        float mag = sqrtf(gx*gx + gy*gy + 1e-10f) * (g1[i]*g1[j]*ginv);
        float ori = atan2f(gy, gx + 1e-10f) + 2.f*PI_F;
        float obig = ori * (8.f/(2.f*PI_F));
        float bo0f = floorf(obig);
        float w1 = obig - bo0f;
        int bo0 = ((int)bo0f) & 7;
        int bo1 = (bo0 + 1) & 7;
        bins[bo0*NPIX + idx] = (1.f - w1)*mag;
        bins[bo1*NPIX + idx] = w1*mag;
    }
    __syncthreads();

    float pacc = 0.f;
    const int t = tid & 127;
    const int half = (HALVES == 2) ? (tid >> 7) : 0;
    if (tid < 128*HALVES) {
        int o = t >> 4;
        int py = (t >> 2) & 3;
        int px = t & 3;
        int sy = py*STRIDE - PAD;
        int sx = px*STRIDE - PAD;
        const float* bo = bins + o*NPIX;
        for (int dr = 0; dr < ROWS; dr++) {
            int di = half*ROWS + dr;
            int i = sy + di;
            if (i < 0 || i >= PS) continue;
            float wi = HALF - fabsf((float)di + 0.5f - HALF);
            for (int dj = 0; dj < BK; dj++) {
                int j = sx + dj;
                if (j < 0 || j >= PS) continue;
                float wj = HALF - fabsf((float)dj + 0.5f - HALF);
                pacc += bo[i*PS + j] * (wi*wj);
            }
        }
    }
    if (HALVES == 2) {
        if (half == 1) pool2[t] = pacc;
        __syncthreads();
    }
    float d = 0.f;
    if (tid < 128) {
        d = pacc;
        if (HALVES == 2) d += pool2[tid];
        d *= 1.0f/(HALF*HALF);
    }

    const int wv = tid >> 6;
    const int ln = tid & 63;

    float v = d*d;
    #pragma unroll
    for (int off = 32; off > 0; off >>= 1) v += __shfl_down(v, off);
    if (ln == 0) wred[wv] = v;
    __syncthreads();
    float nrm = 0.f;
    #pragma unroll
    for (int w2 = 0; w2 < NWAVE; w2++) nrm += wred[w2];
    nrm = sqrtf(nrm);
    __syncthreads();
    d = d / fmaxf(nrm, 1e-12f);
    d = fminf(fmaxf(d, 0.f), 0.2f);

    v = d*d;
    #pragma unroll
    for (int off = 32; off > 0; off >>= 1) v += __shfl_down(v, off);
    if (ln == 0) wred[wv] = v;
    __syncthreads();
    nrm = 0.f;
    #pragma unroll
    for (int w2 = 0; w2 < NWAVE; w2++) nrm += wred[w2];
    nrm = sqrtf(nrm);
    __syncthreads();
    d = d / fmaxf(nrm, 1e-12f);

    v = d;
    #pragma unroll
    for (int off = 32; off > 0; off >>= 1) v += __shfl_down(v, off);
    if (ln == 0) wred[wv] = v;
    __syncthreads();
    float ssum = 0.f;
    #pragma unroll
    for (int w2 = 0; w2 < NWAVE; w2++) ssum += wred[w2];
    d = sqrtf(d / fmaxf(ssum, 1e-12f) + 1e-10f);

    if (tid < 128) out[(size_t)n*128 + tid] = d;
}

// ======================= 1x1 conv, 4 outputs/thread =======================
template<int CO, int S>
__global__ __launch_bounds__(256)
void conv1x1(const float* __restrict__ in, const float* __restrict__ w,
             const float* __restrict__ bias, float* __restrict__ out)
{
    __shared__ float wt[128*CO];
    const int tid = threadIdx.x;
    for (int i = tid; i < 128*CO; i += 256) {
        int c = i / CO, co = i - c*CO;
        wt[i] = w[co*128 + c];
    }
    __syncthreads();
    int idx = blockIdx.x*256 + tid;
    int s = idx % S; int r = idx / S;
    int co4 = r % (CO/4); int b = r / (CO/4);
    int co = co4*4;
    const float* ib = in + (size_t)b*128*S + s;
    float acc0 = bias[co], acc1 = bias[co+1], acc2 = bias[co+2], acc3 = bias[co+3];
    #pragma unroll 8
    for (int c = 0; c < 128; c++) {
        float v = ib[c*S];
        const float4 wv = *(const float4*)&wt[c*CO + co];
        acc0 += v*wv.x; acc1 += v*wv.y; acc2 += v*wv.z; acc3 += v*wv.w;
    }
    float* ob = out + ((size_t)b*CO + co)*S + s;
    ob[0] = acc0; ob[S] = acc1; ob[2*S] = acc2; ob[3*S] = acc3;
}

// ====== ConvTranspose2d(k4,s2,p1) via LDS tile [+GN-on-read] -> partial GN stats ======
template<int CIN0, int CIN1, int COUT, int G, int HIN, int NCH, int RT, int NT,
         bool FUSE, int GIN, int NGIN, int NBLK_IN, int NBLK_OUT>
__global__ __launch_bounds__(NT)
void convt_tiled(const float* __restrict__ in0, const float* __restrict__ in1,
                 const float* __restrict__ w, const float* __restrict__ bias,
                 const float2* __restrict__ pst_in,
                 const float* __restrict__ gnw, const float* __restrict__ gnb,
                 float* __restrict__ out, float2* __restrict__ pst_out)
{
    constexpr int CIN = CIN0 + CIN1;
    constexpr int CG = COUT / G;
    constexpr int NGRP = NCH / CG;
    constexpr int CB = COUT / NCH;
    constexpr int H0 = 2*HIN;
    constexpr int SP = H0*H0;
    constexpr int HIN2 = HIN*HIN;
    constexpr int NR = RT/2 + 2;
    constexpr int WIN = HIN + 2;
    constexpr int TILE = CIN*NR*WIN;
    constexpr int WSTRIDE = CIN*NCH*4 + 4;
    constexpr int NPOS = RT*H0;
    constexpr int NWAVE = NT/64;

    __shared__ float tile[TILE];
    __shared__ float wl2[4*WSTRIDE];
    __shared__ float a_s[CIN0];
    __shared__ float b_s[CIN0];
    __shared__ float wpart[NWAVE][NGRP][2];

    const int tid = threadIdx.x;
    const int by = blockIdx.y;
    const int bx = blockIdx.x;
    const int b  = by / CB;
    const int cb = by - b*CB;
    const int c0 = cb*NCH;
    const int g0 = c0 / CG;
    const int r0 = bx * RT;
    const int row0 = r0/2 - 1;

    if constexpr (FUSE) {
        if (tid < CIN0) {
            int gi = tid / (CIN0/GIN);
            float s0 = 0.f, s1 = 0.f;
            for (int k = 0; k < NBLK_IN; k++) {
                float2 p = pst_in[((size_t)b*GIN + gi)*NBLK_IN + k];
                s0 += p.x; s1 += p.y;
            }
            float mean = s0 * (1.f/NGIN);
            float var  = s1 * (1.f/NGIN) - mean*mean;
            float inv  = rsqrtf(var + 1e-5f);
            float a = inv * gnw[tid];
            a_s[tid] = a;
            b_s[tid] = gnb[tid] - mean*a;
        }
        __syncthreads();
    }

    for (int idx = tid; idx < 4*CIN*NCH*4; idx += NT) {
        int k = idx & 3;
        int t2 = idx >> 2;
        int j = t2 % NCH; t2 /= NCH;
        int ci = t2 % CIN;
        int pq = t2 / CIN;
        int pA = pq >> 1, qA = pq & 1;
        int dy = pA + 2*(k>>1), dx = qA + 2*(k&1);
        wl2[pq*WSTRIDE + (ci*NCH + j)*4 + k] = w[(ci*COUT + c0 + j)*16 + dy*4 + dx];
    }

    const float* i0 = in0 + (size_t)b*CIN0*HIN2;
    for (int idx = tid; idx < TILE; idx += NT) {
        int c = idx % WIN;
        int t2 = idx / WIN;
        int r = t2 % NR;
        int ci = t2 / NR;
        int iy = row0 + r, ix = c - 1;
        float v = 0.f;
        if (iy >= 0 && iy < HIN && ix >= 0 && ix < HIN) {
            if (CIN1 == 0 || ci < CIN0) {
                v = i0[ci*HIN2 + iy*HIN + ix];
                if constexpr (FUSE) v = fmaxf(v*a_s[ci] + b_s[ci], 0.f);
            } else {
                v = in1[((size_t)b*CIN1 + (ci-CIN0))*HIN2 + iy*HIN + ix];
            }
        }
        tile[idx] = v;
    }
    __syncthreads();

    float acc[NCH];
    #pragma unroll
    for (int j = 0; j < NCH; j++) acc[j] = 0.f;

    const bool active = tid < NPOS;
    if (active) {
        int oy = r0 + tid / H0, ox = tid % H0;
        int pA = (oy+1)&1, qA = (ox+1)&1;
        int iyA = (oy+1-pA)>>1, ixA = (ox+1-qA)>>1;
        int rA = iyA - row0;
        int cA = ixA + 1;
        int toff = rA*WIN + cA;
        const float* wbase = wl2 + (pA*2+qA)*WSTRIDE;

        #pragma unroll
        for (int j = 0; j < NCH; j++) acc[j] = bias[c0 + j];

        #pragma unroll 4
        for (int ci = 0; ci < CIN; ci++) {
            const float* tp = tile + ci*(NR*WIN) + toff;
            float l0 = tp[0];
            float l1 = tp[-1];
            float l2 = tp[-WIN];
            float l3 = tp[-WIN-1];
            const float* wr = wbase + ci*NCH*4;
            #pragma unroll
            for (int j = 0; j < NCH; j++) {
                const float4 wv = *(const float4*)(wr + j*4);
                acc[j] += l0*wv.x + l1*wv.y + l2*wv.z + l3*wv.w;
            }
        }
        float* ob = out + ((size_t)b*COUT + c0)*SP + r0*H0 + tid;
        #pragma unroll
        for (int j = 0; j < NCH; j++) ob[j*SP] = acc[j];
    }

    const int wv = tid >> 6;
    const int ln = tid & 63;
    #pragma unroll
    for (int grp = 0; grp < NGRP; grp++) {
        float ps = 0.f, pq2 = 0.f;
        #pragma unroll
        for (int j = 0; j < CG; j++) {
            float v = active ? acc[grp*CG + j] : 0.f;
            ps += v; pq2 += v*v;
        }
        #pragma unroll
        for (int off = 32; off > 0; off >>= 1) {
            ps  += __shfl_down(ps,  off);
            pq2 += __shfl_down(pq2, off);
        }
        if (ln == 0) { wpart[wv][grp][0] = ps; wpart[wv][grp][1] = pq2; }
    }
    __syncthreads();
    if (tid < NGRP) {
        float s0 = 0.f, s1 = 0.f;
        #pragma unroll
        for (int w2 = 0; w2 < NWAVE; w2++) { s0 += wpart[w2][tid][0]; s1 += wpart[w2][tid][1]; }
        pst_out[((size_t)b*G + g0 + tid)*NBLK_OUT + bx] = make_float2(s0, s1);
    }
}

// ====== FUSED: final ConvTranspose2d(4->2, GN-on-read) + joint bilateral + tanh ======
// Each block: 16x16 output tile. Computes the 20x20 pre-tile (incl. reflect halo)
// directly from h4 into LDS, then runs the bilateral window from LDS.
__global__ __launch_bounds__(256)
void final_bilateral(const float* __restrict__ h4, const float* __restrict__ fw,
                     const float* __restrict__ fb, const float2* __restrict__ pst_in,
                     const float* __restrict__ gnw, const float* __restrict__ gnb,
                     const float* __restrict__ x, float* __restrict__ out)
{
    const float g[5] = {0.1200783f, 0.2338817f, 0.2920800f, 0.2338817f, 0.1200783f};
    __shared__ float xs[400], p0s[400], p1s[400];
    __shared__ float wl2[128];
    __shared__ float a_s[4], b_s[4], bl[2], mv[2];

    const int tid = threadIdx.x;
    const int b = blockIdx.z;
    const int ty0 = blockIdx.y*16;
    const int tx0 = blockIdx.x*16;
    const float* xb = x + (size_t)b*50176;

    if (tid < 128) {
        int k = tid & 3;
        int t = tid >> 2;
        int co = t & 1; t >>= 1;
        int ci = t & 3;
        int pq = t >> 2;
        int pA = pq >> 1, qA = pq & 1;
        int dy = pA + 2*(k>>1), dx = qA + 2*(k&1);
        wl2[tid] = fw[(ci*2 + co)*16 + dy*4 + dx];
    }
    if (tid < 2) bl[tid] = fb[tid];
    if (tid >= 192) {   // one wave reduces the 56 GN partials
        int k0 = tid - 192;
        float s0 = 0.f, s1 = 0.f;
        if (k0 < 56) {
            float2 p = pst_in[(size_t)b*56 + k0];
            s0 = p.x; s1 = p.y;
        }
        #pragma unroll
        for (int off = 32; off > 0; off >>= 1) {
            s0 += __shfl_down(s0, off);
            s1 += __shfl_down(s1, off);
        }
        if (k0 == 0) {
            float mean = s0 * (1.f/50176.f);
            float var  = s1 * (1.f/50176.f) - mean*mean;
            mv[0] = mean;
            mv[1] = rsqrtf(var + 1e-5f);
        }
    }
    __syncthreads();
    if (tid < 4) {
        float a = mv[1] * gnw[tid];
        a_s[tid] = a;
        b_s[tid] = gnb[tid] - mv[0]*a;
    }
    __syncthreads();

    // compute pre (2ch) + stage x on the reflected 20x20 tile
    const float* ib = h4 + (size_t)b*4*12544;
    for (int idx = tid; idx < 400; idx += 256) {
        int r = idx / 20, cc = idx - r*20;
        int oy = ty0 - 2 + r;  oy = oy < 0 ? -oy : (oy > 223 ? 446 - oy : oy);
        int ox = tx0 - 2 + cc; ox = ox < 0 ? -ox : (ox > 223 ? 446 - ox : ox);
        xs[idx] = xb[oy*224 + ox];

        int pA = (oy+1)&1, iyA = (oy+1-pA)>>1, iyB = iyA-1;
        int qA = (ox+1)&1, ixA = (ox+1-qA)>>1, ixB = ixA-1;
        float mYA = (iyA < 112) ? 1.f : 0.f;
        float mYB = (iyB >= 0)  ? 1.f : 0.f;
        float mXA = (ixA < 112) ? 1.f : 0.f;
        float mXB = (ixB >= 0)  ? 1.f : 0.f;
        float m0 = mYA*mXA, m1 = mYA*mXB, m2 = mYB*mXA, m3 = mYB*mXB;
        int iyAc = min(iyA, 111), iyBc = max(iyB, 0);
        int ixAc = min(ixA, 111), ixBc = max(ixB, 0);
        int oAA = iyAc*112 + ixAc, oAB = iyAc*112 + ixBc;
        int oBA = iyBc*112 + ixAc, oBB = iyBc*112 + ixBc;
        const float* wbase = wl2 + (pA*2+qA)*32;

        float acc0 = bl[0], acc1 = bl[1];
        #pragma unroll
        for (int ci = 0; ci < 4; ci++) {
            const float* ip = ib + ci*12544;
            float a = a_s[ci], bb = b_s[ci];
            float l0 = fmaxf(ip[oAA]*a + bb, 0.f);
            float l1 = fmaxf(ip[oAB]*a + bb, 0.f);
            float l2 = fmaxf(ip[oBA]*a + bb, 0.f);
            float l3 = fmaxf(ip[oBB]*a + bb, 0.f);
            float t0 = l0*m0, t1 = l1*m1, t2 = l2*m2, t3 = l3*m3;
            const float4 w0 = *(const float4*)(wbase + ci*8);
            const float4 w1 = *(const float4*)(wbase + ci*8 + 4);
            acc0 += t0*w0.x + t1*w0.y + t2*w0.z + t3*w0.w;
            acc1 += t0*w1.x + t1*w1.y + t2*w1.z + t3*w1.w;
        }
        p0s[idx] = acc0;
        p1s[idx] = acc1;
    }
    __syncthreads();

    int ly = tid >> 4, lx = tid & 15;
    int base = (ly+2)*20 + (lx+2);
    float center = xs[base];
    float wsum = 0.f, a0 = 0.f, a1 = 0.f;
    #pragma unroll
    for (int di = -2; di <= 2; di++){
        #pragma unroll
        for (int dj = -2; dj <= 2; dj++){
            int o = base + di*20 + dj;
            float dg = xs[o] - center;
            float wgt = g[di+2]*g[dj+2]*__expf(-200.f*dg*dg);
            wsum += wgt;
            a0 += wgt * p0s[o];
            a1 += wgt * p1s[o];
        }
    }
    float inv = 1.0f / wsum;
    int s = (ty0 + ly)*224 + (tx0 + lx);
    out[(size_t)(b*2)*50176 + s]     = tanhf(a0*inv)*0.436f;
    out[(size_t)(b*2+1)*50176 + s]   = tanhf(a1*inv)*0.615f;
}

// ======================= launch =======================
extern "C" void kernel_launch(void* const* d_in, const int* in_sizes, int n_in,
                              void* d_out, int out_size, void* d_ws, size_t ws_size,
                              hipStream_t stream) {
    (void)in_sizes; (void)n_in; (void)out_size; (void)ws_size;
    const float* x   = (const float*)d_in[0];
    const float* d1w = (const float*)d_in[1];
    const float* d1b = (const float*)d_in[2];
    const float* g1w = (const float*)d_in[3];
    const float* g1b = (const float*)d_in[4];
    const float* s1w = (const float*)d_in[5];
    const float* s1b = (const float*)d_in[6];
    const float* d2w = (const float*)d_in[7];
    const float* d2b = (const float*)d_in[8];
    const float* g2w = (const float*)d_in[9];
    const float* g2b = (const float*)d_in[10];
    const float* s2w = (const float*)d_in[11];
    const float* s2b = (const float*)d_in[12];
    const float* d3w = (const float*)d_in[13];
    const float* d3b = (const float*)d_in[14];
    const float* g3w = (const float*)d_in[15];
    const float* g3b = (const float*)d_in[16];
    const float* d4w = (const float*)d_in[17];
    const float* d4b = (const float*)d_in[18];
    const float* g4w = (const float*)d_in[19];
    const float* g4b = (const float*)d_in[20];
    const float* fw  = (const float*)d_in[21];
    const float* fb  = (const float*)d_in[22];
    float* out = (float*)d_out;

    float* ws  = (float*)d_ws;
    float* s7  = ws;                  // 16*128*49      = 100352
    float* s14 = s7  + 100352;        // 16*128*196     = 401408
    float* s28 = s14 + 401408;        // 16*128*784     = 1605632
    float* sk1 = s28 + 1605632;       // 16*32*196      = 100352
    float* sk2 = sk1 + 100352;        // 16*16*784      = 200704
    float* h1  = sk2 + 200704;        // 16*32*196      = 100352
    float* h2  = h1  + 100352;        // 16*16*784      = 200704
    float* h3  = h2  + 200704;        // 16*8*3136      = 401408
    float* h4  = h3  + 401408;        // 16*4*12544     = 802816
    float2* pst1 = (float2*)(h4 + 802816);     // 16*8  * 1  = 128 pairs
    float2* pst2 = pst1 + 128;                 // 16*4  * 7  = 448 pairs
    float2* pst3 = pst2 + 448;                 // 16*2  * 14 = 448 pairs
    float2* pst4 = pst3 + 448;                 // 16*1  * 56 = 896 pairs

    // ---- SIFT features ----
    sift_kernel<32, 7, 256><<<784,   256, 0, stream>>>(x, s7);
    sift_kernel<16,14, 256><<<3136,  256, 0, stream>>>(x, s14);
    sift8_wave<<<3136, 256, 0, stream>>>(x, s28);

    // ---- skip connections ----
    conv1x1<32, 196><<<98,  256, 0, stream>>>(s14, s1w, s1b, sk1);
    conv1x1<16, 784><<<196, 256, 0, stream>>>(s28, s2w, s2b, sk2);

    // L1: convT(128->32, 7->14), GN(8).
    convt_tiled<128, 0, 32, 8,  7, 4, 14, 256, false, 1, 1, 1, 1>
        <<<dim3(1, 16*8), 256, 0, stream>>>(s7, nullptr, d1w, d1b, nullptr, nullptr, nullptr, h1, pst1);
    // L2: convT(64->16, 14->28), GN(4).
    convt_tiled< 32,32, 16, 4, 14, 8,  4, 128, true, 8, 784, 1, 7>
        <<<dim3(7, 16*2), 128, 0, stream>>>(h1, sk1, d2w, d2b, pst1, g1w, g1b, h2, pst2);
    // L3: convT(32->8, 28->56), GN(2).
    convt_tiled< 16,16,  8, 2, 28, 8,  4, 256, true, 4, 3136, 7, 14>
        <<<dim3(14, 16), 256, 0, stream>>>(h2, sk2, d3w, d3b, pst2, g2w, g2b, h3, pst3);
    // L4: convT(8->4, 56->112), GN(1).
    convt_tiled<  8, 0,  4, 1, 56, 4,  2, 256, true, 2, 12544, 14, 56>
        <<<dim3(56, 16), 256, 0, stream>>>(h3, nullptr, d4w, d4b, pst3, g3w, g3b, h4, pst4);

    // fused head: final convT (GN-on-read of h4) + bilateral + tanh
    final_bilateral<<<dim3(14, 14, 16), 256, 0, stream>>>(h4, fw, fb, pst4, g4w, g4b, x, out);
}

// Round 10
// 239.778 us; speedup vs baseline: 1.0456x; 1.0456x over previous
//
#include <hip/hip_runtime.h>
#include <math.h>

#define PI_F 3.14159265358979323846f

// ================= SIFT block bodies (device, inlined into sift_all) =================
template<int PS, int K>
__device__ __forceinline__
void sift_block(const float* __restrict__ x, float* __restrict__ out,
                int n, float* lds)
{
    constexpr int NT = 256;
    constexpr int NPIX = PS*PS;
    constexpr int BK = 2*(PS/5);
    constexpr int STRIDE = PS/4;
    constexpr int PAD = BK/4;
    constexpr float HALF = BK*0.5f;
    constexpr int NWAVE = NT/64;
    constexpr int ROWS = BK/2;          // pooling split in 2 halves

    float* patch = lds;                  // NPIX
    float* bins  = patch + NPIX;         // 8*NPIX
    float* g1    = bins + 8*NPIX;        // PS
    float* pool2 = g1 + PS;              // 128
    float* wred  = pool2 + 128;          // NWAVE
    float* gsum_s = wred + NWAVE;        // 1

    const int tid = threadIdx.x;
    const int b = n / (K*K);
    const int c = n % (K*K);
    const int ki = c / K;
    const int kj = c % K;

    const float* xb = x + (size_t)b*224*224;
    for (int idx = tid; idx < NPIX; idx += NT) {
        int i = idx / PS, j = idx - i*PS;
        patch[idx] = xb[(i*K + ki)*224 + (j*K + kj)];
    }
    if (tid < PS) {
        const float sigma = (float)PS * 0.70710678118654752440f;
        float xv = (float)tid - (PS-1)*0.5f;
        float t = xv / sigma;
        g1[tid] = expf(-0.5f*t*t);
    }
    for (int idx = tid; idx < 8*NPIX; idx += NT) bins[idx] = 0.f;
    __syncthreads();
    if (tid == 0) {
        float s = 0.f;
        for (int i = 0; i < PS; i++) s += g1[i];
        gsum_s[0] = s;
    }
    __syncthreads();
    const float ginv = 1.0f / (gsum_s[0]*gsum_s[0]);

    for (int idx = tid; idx < NPIX; idx += NT) {
        int i = idx / PS, j = idx - i*PS;
        int jm = j > 0 ? j-1 : 0, jp = j < PS-1 ? j+1 : PS-1;
        int im = i > 0 ? i-1 : 0, ip = i < PS-1 ? i+1 : PS-1;
        float gx = 0.5f*(patch[i*PS+jp] - patch[i*PS+jm]);
        float gy = 0.5f*(patch[ip*PS+j] - patch[im*PS+j]);
        float mag = sqrtf(gx*gx + gy*gy + 1e-10f) * (g1[i]*g1[j]*ginv);
        float ori = atan2f(gy, gx + 1e-10f) + 2.f*PI_F;
        float obig = ori * (8.f/(2.f*PI_F));
        float bo0f = floorf(obig);
        float w1 = obig - bo0f;
        int bo0 = ((int)bo0f) & 7;
        int bo1 = (bo0 + 1) & 7;
        bins[bo0*NPIX + idx] = (1.f - w1)*mag;
        bins[bo1*NPIX + idx] = w1*mag;
    }
    __syncthreads();

    // Triangular pooling, split across 2 thread halves
    float pacc = 0.f;
    const int t = tid & 127;
    const int half = tid >> 7;
    {
        int o = t >> 4;
        int py = (t >> 2) & 3;
        int px = t & 3;
        int sy = py*STRIDE - PAD;
        int sx = px*STRIDE - PAD;
        const float* bo = bins + o*NPIX;
        for (int dr = 0; dr < ROWS; dr++) {
            int di = half*ROWS + dr;
            int i = sy + di;
            if (i < 0 || i >= PS) continue;
            float wi = HALF - fabsf((float)di + 0.5f - HALF);
            for (int dj = 0; dj < BK; dj++) {
                int j = sx + dj;
                if (j < 0 || j >= PS) continue;
                float wj = HALF - fabsf((float)dj + 0.5f - HALF);
                pacc += bo[i*PS + j] * (wi*wj);
            }
        }
    }
    if (half == 1) pool2[t] = pacc;
    __syncthreads();
    float d = 0.f;
    if (tid < 128) {
        d = (pacc + pool2[tid]) * (1.0f/(HALF*HALF));
    }

    const int wv = tid >> 6;
    const int ln = tid & 63;

    float v = d*d;
    #pragma unroll
    for (int off = 32; off > 0; off >>= 1) v += __shfl_down(v, off);
    if (ln == 0) wred[wv] = v;
    __syncthreads();
    float nrm = 0.f;
    #pragma unroll
    for (int w2 = 0; w2 < NWAVE; w2++) nrm += wred[w2];
    nrm = sqrtf(nrm);
    __syncthreads();
    d = d / fmaxf(nrm, 1e-12f);
    d = fminf(fmaxf(d, 0.f), 0.2f);

    v = d*d;
    #pragma unroll
    for (int off = 32; off > 0; off >>= 1) v += __shfl_down(v, off);
    if (ln == 0) wred[wv] = v;
    __syncthreads();
    nrm = 0.f;
    #pragma unroll
    for (int w2 = 0; w2 < NWAVE; w2++) nrm += wred[w2];
    nrm = sqrtf(nrm);
    __syncthreads();
    d = d / fmaxf(nrm, 1e-12f);

    v = d;   // d >= 0 -> sum == sum(|d|)
    #pragma unroll
    for (int off = 32; off > 0; off >>= 1) v += __shfl_down(v, off);
    if (ln == 0) wred[wv] = v;
    __syncthreads();
    float ssum = 0.f;
    #pragma unroll
    for (int w2 = 0; w2 < NWAVE; w2++) ssum += wred[w2];
    d = sqrtf(d / fmaxf(ssum, 1e-12f) + 1e-10f);

    if (tid < 128) out[(size_t)n*128 + tid] = d;
}

// PS=8 (K=28): one wave per patch, register-only (uniform factors cancel at L2-norm)
__device__ __forceinline__
void sift8_block(const float* __restrict__ x, float* __restrict__ out, int bid)
{
    const int tid = threadIdx.x;
    const int l = tid & 63;
    const int wv = tid >> 6;
    const int n = bid*4 + wv;             // 12544 patches
    const int b = n / 784;
    const int c = n % 784;
    const int ki = c / 28, kj = c % 28;
    const int i = l >> 3, j = l & 7;

    const float* xb = x + (size_t)b*50176;
    float v = xb[(i*28 + ki)*224 + (j*28 + kj)];

    int lL = (j > 0) ? l-1 : l;
    int lR = (j < 7) ? l+1 : l;
    int lU = (i > 0) ? l-8 : l;
    int lD = (i < 7) ? l+8 : l;
    float pL = __shfl(v, lL);
    float pR = __shfl(v, lR);
    float pU = __shfl(v, lU);
    float pD = __shfl(v, lD);
    float gx = 0.5f*(pR - pL);
    float gy = 0.5f*(pD - pU);

    float ti = ((float)i - 3.5f) * (1.f/5.65685424949238f);
    float tj = ((float)j - 3.5f) * (1.f/5.65685424949238f);
    float wsp = __expf(-0.5f*(ti*ti + tj*tj));
    float mag = sqrtf(gx*gx + gy*gy + 1e-10f) * wsp;
    float ori = atan2f(gy, gx + 1e-10f) + 2.f*PI_F;
    float obig = ori * (8.f/(2.f*PI_F));
    float bo0f = floorf(obig);
    float w1 = obig - bo0f;
    int bo0 = ((int)bo0f) & 7;
    int bo1 = (bo0 + 1) & 7;
    float c0 = (1.f - w1)*mag;
    float c1 = w1*mag;

    const int t = ((i & 1) << 1) | (j & 1);
    float d0 = 0.f, d1 = 0.f;
    #pragma unroll
    for (int o = 0; o < 8; o++) {
        float val = (bo0 == o ? c0 : 0.f) + (bo1 == o ? c1 : 0.f);
        val += __shfl_xor(val, 1);
        val += __shfl_xor(val, 8);
        if (o == 2*t)     d0 = val;
        if (o == 2*t + 1) d1 = val;
    }

    float s = d0*d0 + d1*d1;
    #pragma unroll
    for (int off = 32; off > 0; off >>= 1) s += __shfl_xor(s, off);
    float nrm = fmaxf(sqrtf(s), 1e-12f);
    d0 /= nrm; d1 /= nrm;
    d0 = fminf(fmaxf(d0, 0.f), 0.2f);
    d1 = fminf(fmaxf(d1, 0.f), 0.2f);
    s = d0*d0 + d1*d1;
    #pragma unroll
    for (int off = 32; off > 0; off >>= 1) s += __shfl_xor(s, off);
    nrm = fmaxf(sqrtf(s), 1e-12f);
    d0 /= nrm; d1 /= nrm;
    s = d0 + d1;
    #pragma unroll
    for (int off = 32; off > 0; off >>= 1) s += __shfl_xor(s, off);
    s = fmaxf(s, 1e-12f);
    d0 = sqrtf(d0/s + 1e-10f);
    d1 = sqrtf(d1/s + 1e-10f);

    int cell = (i >> 1)*4 + (j >> 1);
    float* ob = out + (size_t)n*128 + cell;
    ob[(2*t)*16]     = d0;
    ob[(2*t + 1)*16] = d1;
}

// ============ ONE dispatch for all three SIFT scales (block-range dispatch) ============
__global__ __launch_bounds__(256)
void sift_all(const float* __restrict__ x, float* __restrict__ s7,
              float* __restrict__ s14, float* __restrict__ s28)
{
    __shared__ float lds[9408];   // 37 KB: union of PS=32 (9381 fl) / PS=16 (2453 fl)
    const int bid = blockIdx.x;
    if (bid < 784) {
        sift_block<32, 7>(x, s7, bid, lds);
    } else if (bid < 3920) {
        sift_block<16, 14>(x, s14, bid - 784, lds);
    } else {
        sift8_block(x, s28, bid - 3920);
    }
}

// ================= conv1x1 block body (device) =================
template<int CO, int S>
__device__ __forceinline__
void conv1x1_block(const float* __restrict__ in, const float* __restrict__ w,
                   const float* __restrict__ bias, float* __restrict__ out,
                   int bid, float* wt)
{
    const int tid = threadIdx.x;
    for (int i = tid; i < 128*CO; i += 256) {
        int c = i / CO, co = i - c*CO;
        wt[i] = w[co*128 + c];       // transposed: wt[c*CO+co]
    }
    __syncthreads();
    int idx = bid*256 + tid;         // 16*(CO/4)*S threads exactly
    int s = idx % S; int r = idx / S;
    int co4 = r % (CO/4); int b = r / (CO/4);
    int co = co4*4;
    const float* ib = in + (size_t)b*128*S + s;
    float acc0 = bias[co], acc1 = bias[co+1], acc2 = bias[co+2], acc3 = bias[co+3];
    #pragma unroll 8
    for (int c = 0; c < 128; c++) {
        float v = ib[c*S];
        const float4 wv = *(const float4*)&wt[c*CO + co];
        acc0 += v*wv.x; acc1 += v*wv.y; acc2 += v*wv.z; acc3 += v*wv.w;
    }
    float* ob = out + ((size_t)b*CO + co)*S + s;
    ob[0] = acc0; ob[S] = acc1; ob[2*S] = acc2; ob[3*S] = acc3;
}

// ============ ONE dispatch for both skip conv1x1s ============
__global__ __launch_bounds__(256)
void skip_all(const float* __restrict__ s14, const float* __restrict__ s28,
              const float* __restrict__ s1w, const float* __restrict__ s1b,
              const float* __restrict__ s2w, const float* __restrict__ s2b,
              float* __restrict__ sk1, float* __restrict__ sk2)
{
    __shared__ float wt[4096];      // max(128*32, 128*16)
    const int bid = blockIdx.x;
    if (bid < 98) conv1x1_block<32, 196>(s14, s1w, s1b, sk1, bid, wt);
    else          conv1x1_block<16, 784>(s28, s2w, s2b, sk2, bid - 98, wt);
}

// ====== ConvTranspose2d(k4,s2,p1) via LDS tile [+GN-on-read] -> partial GN stats ======
template<int CIN0, int CIN1, int COUT, int G, int HIN, int NCH, int RT, int NT,
         bool FUSE, int GIN, int NGIN, int NBLK_IN, int NBLK_OUT>
__global__ __launch_bounds__(NT)
void convt_tiled(const float* __restrict__ in0, const float* __restrict__ in1,
                 const float* __restrict__ w, const float* __restrict__ bias,
                 const float2* __restrict__ pst_in,
                 const float* __restrict__ gnw, const float* __restrict__ gnb,
                 float* __restrict__ out, float2* __restrict__ pst_out)
{
    constexpr int CIN = CIN0 + CIN1;
    constexpr int CG = COUT / G;
    constexpr int NGRP = NCH / CG;
    constexpr int CB = COUT / NCH;
    constexpr int H0 = 2*HIN;
    constexpr int SP = H0*H0;
    constexpr int HIN2 = HIN*HIN;
    constexpr int NR = RT/2 + 2;
    constexpr int WIN = HIN + 2;
    constexpr int TILE = CIN*NR*WIN;
    constexpr int WSTRIDE = CIN*NCH*4 + 4;
    constexpr int NPOS = RT*H0;
    constexpr int NWAVE = NT/64;

    __shared__ float tile[TILE];
    __shared__ float wl2[4*WSTRIDE];
    __shared__ float a_s[CIN0];
    __shared__ float b_s[CIN0];
    __shared__ float wpart[NWAVE][NGRP][2];

    const int tid = threadIdx.x;
    const int by = blockIdx.y;
    const int bx = blockIdx.x;
    const int b  = by / CB;
    const int cb = by - b*CB;
    const int c0 = cb*NCH;
    const int g0 = c0 / CG;
    const int r0 = bx * RT;
    const int row0 = r0/2 - 1;

    if constexpr (FUSE) {
        if (tid < CIN0) {
            int gi = tid / (CIN0/GIN);
            float s0 = 0.f, s1 = 0.f;
            for (int k = 0; k < NBLK_IN; k++) {
                float2 p = pst_in[((size_t)b*GIN + gi)*NBLK_IN + k];
                s0 += p.x; s1 += p.y;
            }
            float mean = s0 * (1.f/NGIN);
            float var  = s1 * (1.f/NGIN) - mean*mean;
            float inv  = rsqrtf(var + 1e-5f);
            float a = inv * gnw[tid];
            a_s[tid] = a;
            b_s[tid] = gnb[tid] - mean*a;
        }
        __syncthreads();
    }

    for (int idx = tid; idx < 4*CIN*NCH*4; idx += NT) {
        int k = idx & 3;
        int t2 = idx >> 2;
        int j = t2 % NCH; t2 /= NCH;
        int ci = t2 % CIN;
        int pq = t2 / CIN;
        int pA = pq >> 1, qA = pq & 1;
        int dy = pA + 2*(k>>1), dx = qA + 2*(k&1);
        wl2[pq*WSTRIDE + (ci*NCH + j)*4 + k] = w[(ci*COUT + c0 + j)*16 + dy*4 + dx];
    }

    const float* i0 = in0 + (size_t)b*CIN0*HIN2;
    for (int idx = tid; idx < TILE; idx += NT) {
        int c = idx % WIN;
        int t2 = idx / WIN;
        int r = t2 % NR;
        int ci = t2 / NR;
        int iy = row0 + r, ix = c - 1;
        float v = 0.f;
        if (iy >= 0 && iy < HIN && ix >= 0 && ix < HIN) {
            if (CIN1 == 0 || ci < CIN0) {
                v = i0[ci*HIN2 + iy*HIN + ix];
                if constexpr (FUSE) v = fmaxf(v*a_s[ci] + b_s[ci], 0.f);
            } else {
                v = in1[((size_t)b*CIN1 + (ci-CIN0))*HIN2 + iy*HIN + ix];
            }
        }
        tile[idx] = v;
    }
    __syncthreads();

    float acc[NCH];
    #pragma unroll
    for (int j = 0; j < NCH; j++) acc[j] = 0.f;

    const bool active = tid < NPOS;
    if (active) {
        int oy = r0 + tid / H0, ox = tid % H0;
        int pA = (oy+1)&1, qA = (ox+1)&1;
        int iyA = (oy+1-pA)>>1, ixA = (ox+1-qA)>>1;
        int rA = iyA - row0;
        int cA = ixA + 1;
        int toff = rA*WIN + cA;
        const float* wbase = wl2 + (pA*2+qA)*WSTRIDE;

        #pragma unroll
        for (int j = 0; j < NCH; j++) acc[j] = bias[c0 + j];

        #pragma unroll 4
        for (int ci = 0; ci < CIN; ci++) {
            const float* tp = tile + ci*(NR*WIN) + toff;
            float l0 = tp[0];
            float l1 = tp[-1];
            float l2 = tp[-WIN];
            float l3 = tp[-WIN-1];
            const float* wr = wbase + ci*NCH*4;
            #pragma unroll
            for (int j = 0; j < NCH; j++) {
                const float4 wv = *(const float4*)(wr + j*4);
                acc[j] += l0*wv.x + l1*wv.y + l2*wv.z + l3*wv.w;
            }
        }
        float* ob = out + ((size_t)b*COUT + c0)*SP + r0*H0 + tid;
        #pragma unroll
        for (int j = 0; j < NCH; j++) ob[j*SP] = acc[j];
    }

    const int wv = tid >> 6;
    const int ln = tid & 63;
    #pragma unroll
    for (int grp = 0; grp < NGRP; grp++) {
        float ps = 0.f, pq2 = 0.f;
        #pragma unroll
        for (int j = 0; j < CG; j++) {
            float v = active ? acc[grp*CG + j] : 0.f;
            ps += v; pq2 += v*v;
        }
        #pragma unroll
        for (int off = 32; off > 0; off >>= 1) {
            ps  += __shfl_down(ps,  off);
            pq2 += __shfl_down(pq2, off);
        }
        if (ln == 0) { wpart[wv][grp][0] = ps; wpart[wv][grp][1] = pq2; }
    }
    __syncthreads();
    if (tid < NGRP) {
        float s0 = 0.f, s1 = 0.f;
        #pragma unroll
        for (int w2 = 0; w2 < NWAVE; w2++) { s0 += wpart[w2][tid][0]; s1 += wpart[w2][tid][1]; }
        pst_out[((size_t)b*G + g0 + tid)*NBLK_OUT + bx] = make_float2(s0, s1);
    }
}

// ====== FUSED: final ConvTranspose2d(4->2, GN-on-read) + joint bilateral + tanh ======
__global__ __launch_bounds__(256)
void final_bilateral(const float* __restrict__ h4, const float* __restrict__ fw,
                     const float* __restrict__ fb, const float2* __restrict__ pst_in,
                     const float* __restrict__ gnw, const float* __restrict__ gnb,
                     const float* __restrict__ x, float* __restrict__ out)
{
    const float g[5] = {0.1200783f, 0.2338817f, 0.2920800f, 0.2338817f, 0.1200783f};
    __shared__ float xs[400], p0s[400], p1s[400];
    __shared__ float wl2[128];
    __shared__ float a_s[4], b_s[4], bl[2], mv[2];

    const int tid = threadIdx.x;
    const int b = blockIdx.z;
    const int ty0 = blockIdx.y*16;
    const int tx0 = blockIdx.x*16;
    const float* xb = x + (size_t)b*50176;

    if (tid < 128) {
        int k = tid & 3;
        int t = tid >> 2;
        int co = t & 1; t >>= 1;
        int ci = t & 3;
        int pq = t >> 2;
        int pA = pq >> 1, qA = pq & 1;
        int dy = pA + 2*(k>>1), dx = qA + 2*(k&1);
        wl2[tid] = fw[(ci*2 + co)*16 + dy*4 + dx];
    }
    if (tid < 2) bl[tid] = fb[tid];
    if (tid >= 192) {
        int k0 = tid - 192;
        float s0 = 0.f, s1 = 0.f;
        if (k0 < 56) {
            float2 p = pst_in[(size_t)b*56 + k0];
            s0 = p.x; s1 = p.y;
        }
        #pragma unroll
        for (int off = 32; off > 0; off >>= 1) {
            s0 += __shfl_down(s0, off);
            s1 += __shfl_down(s1, off);
        }
        if (k0 == 0) {
            float mean = s0 * (1.f/50176.f);
            float var  = s1 * (1.f/50176.f) - mean*mean;
            mv[0] = mean;
            mv[1] = rsqrtf(var + 1e-5f);
        }
    }
    __syncthreads();
    if (tid < 4) {
        float a = mv[1] * gnw[tid];
        a_s[tid] = a;
        b_s[tid] = gnb[tid] - mv[0]*a;
    }
    __syncthreads();

    const float* ib = h4 + (size_t)b*4*12544;
    for (int idx = tid; idx < 400; idx += 256) {
        int r = idx / 20, cc = idx - r*20;
        int oy = ty0 - 2 + r;  oy = oy < 0 ? -oy : (oy > 223 ? 446 - oy : oy);
        int ox = tx0 - 2 + cc; ox = ox < 0 ? -ox : (ox > 223 ? 446 - ox : ox);
        xs[idx] = xb[oy*224 + ox];

        int pA = (oy+1)&1, iyA = (oy+1-pA)>>1, iyB = iyA-1;
        int qA = (ox+1)&1, ixA = (ox+1-qA)>>1, ixB = ixA-1;
        float mYA = (iyA < 112) ? 1.f : 0.f;
        float mYB = (iyB >= 0)  ? 1.f : 0.f;
        float mXA = (ixA < 112) ? 1.f : 0.f;
        float mXB = (ixB >= 0)  ? 1.f : 0.f;
        float m0 = mYA*mXA, m1 = mYA*mXB, m2 = mYB*mXA, m3 = mYB*mXB;
        int iyAc = min(iyA, 111), iyBc = max(iyB, 0);
        int ixAc = min(ixA, 111), ixBc = max(ixB, 0);
        int oAA = iyAc*112 + ixAc, oAB = iyAc*112 + ixBc;
        int oBA = iyBc*112 + ixAc, oBB = iyBc*112 + ixBc;
        const float* wbase = wl2 + (pA*2+qA)*32;

        float acc0 = bl[0], acc1 = bl[1];
        #pragma unroll
        for (int ci = 0; ci < 4; ci++) {
            const float* ip = ib + ci*12544;
            float a = a_s[ci], bb = b_s[ci];
            float l0 = fmaxf(ip[oAA]*a + bb, 0.f);
            float l1 = fmaxf(ip[oAB]*a + bb, 0.f);
            float l2 = fmaxf(ip[oBA]*a + bb, 0.f);
            float l3 = fmaxf(ip[oBB]*a + bb, 0.f);
            float t0 = l0*m0, t1 = l1*m1, t2 = l2*m2, t3 = l3*m3;
            const float4 w0 = *(const float4*)(wbase + ci*8);
            const float4 w1 = *(const float4*)(wbase + ci*8 + 4);
            acc0 += t0*w0.x + t1*w0.y + t2*w0.z + t3*w0.w;
            acc1 += t0*w1.x + t1*w1.y + t2*w1.z + t3*w1.w;
        }
        p0s[idx] = acc0;
        p1s[idx] = acc1;
    }
    __syncthreads();

    int ly = tid >> 4, lx = tid & 15;
    int base = (ly+2)*20 + (lx+2);
    float center = xs[base];
    float wsum = 0.f, a0 = 0.f, a1 = 0.f;
    #pragma unroll
    for (int di = -2; di <= 2; di++){
        #pragma unroll
        for (int dj = -2; dj <= 2; dj++){
            int o = base + di*20 + dj;
            float dg = xs[o] - center;
            float wgt = g[di+2]*g[dj+2]*__expf(-200.f*dg*dg);
            wsum += wgt;
            a0 += wgt * p0s[o];
            a1 += wgt * p1s[o];
        }
    }
    float inv = 1.0f / wsum;
    int s = (ty0 + ly)*224 + (tx0 + lx);
    out[(size_t)(b*2)*50176 + s]     = tanhf(a0*inv)*0.436f;
    out[(size_t)(b*2+1)*50176 + s]   = tanhf(a1*inv)*0.615f;
}

// ======================= launch =======================
extern "C" void kernel_launch(void* const* d_in, const int* in_sizes, int n_in,
                              void* d_out, int out_size, void* d_ws, size_t ws_size,
                              hipStream_t stream) {
    (void)in_sizes; (void)n_in; (void)out_size; (void)ws_size;
    const float* x   = (const float*)d_in[0];
    const float* d1w = (const float*)d_in[1];
    const float* d1b = (const float*)d_in[2];
    const float* g1w = (const float*)d_in[3];
    const float* g1b = (const float*)d_in[4];
    const float* s1w = (const float*)d_in[5];
    const float* s1b = (const float*)d_in[6];
    const float* d2w = (const float*)d_in[7];
    const float* d2b = (const float*)d_in[8];
    const float* g2w = (const float*)d_in[9];
    const float* g2b = (const float*)d_in[10];
    const float* s2w = (const float*)d_in[11];
    const float* s2b = (const float*)d_in[12];
    const float* d3w = (const float*)d_in[13];
    const float* d3b = (const float*)d_in[14];
    const float* g3w = (const float*)d_in[15];
    const float* g3b = (const float*)d_in[16];
    const float* d4w = (const float*)d_in[17];
    const float* d4b = (const float*)d_in[18];
    const float* g4w = (const float*)d_in[19];
    const float* g4b = (const float*)d_in[20];
    const float* fw  = (const float*)d_in[21];
    const float* fb  = (const float*)d_in[22];
    float* out = (float*)d_out;

    float* ws  = (float*)d_ws;
    float* s7  = ws;                  // 16*128*49      = 100352
    float* s14 = s7  + 100352;        // 16*128*196     = 401408
    float* s28 = s14 + 401408;        // 16*128*784     = 1605632
    float* sk1 = s28 + 1605632;       // 16*32*196      = 100352
    float* sk2 = sk1 + 100352;        // 16*16*784      = 200704
    float* h1  = sk2 + 200704;        // 16*32*196      = 100352
    float* h2  = h1  + 100352;        // 16*16*784      = 200704
    float* h3  = h2  + 200704;        // 16*8*3136      = 401408
    float* h4  = h3  + 401408;        // 16*4*12544     = 802816
    float2* pst1 = (float2*)(h4 + 802816);     // 16*8  * 1  = 128 pairs
    float2* pst2 = pst1 + 128;                 // 16*4  * 7  = 448 pairs
    float2* pst3 = pst2 + 448;                 // 16*2  * 14 = 448 pairs
    float2* pst4 = pst3 + 448;                 // 16*1  * 56 = 896 pairs

    // ---- all SIFT scales in ONE dispatch (784 + 3136 + 3136 blocks) ----
    sift_all<<<7056, 256, 0, stream>>>(x, s7, s14, s28);

    // ---- both skip conv1x1s in ONE dispatch (98 + 196 blocks) ----
    skip_all<<<294, 256, 0, stream>>>(s14, s28, s1w, s1b, s2w, s2b, sk1, sk2);

    // L1: convT(128->32, 7->14), GN(8).
    convt_tiled<128, 0, 32, 8,  7, 4, 14, 256, false, 1, 1, 1, 1>
        <<<dim3(1, 16*8), 256, 0, stream>>>(s7, nullptr, d1w, d1b, nullptr, nullptr, nullptr, h1, pst1);
    // L2: convT(64->16, 14->28), GN(4).
    convt_tiled< 32,32, 16, 4, 14, 8,  4, 128, true, 8, 784, 1, 7>
        <<<dim3(7, 16*2), 128, 0, stream>>>(h1, sk1, d2w, d2b, pst1, g1w, g1b, h2, pst2);
    // L3: convT(32->8, 28->56), GN(2).
    convt_tiled< 16,16,  8, 2, 28, 8,  4, 256, true, 4, 3136, 7, 14>
        <<<dim3(14, 16), 256, 0, stream>>>(h2, sk2, d3w, d3b, pst2, g2w, g2b, h3, pst3);
    // L4: convT(8->4, 56->112), GN(1).
    convt_tiled<  8, 0,  4, 1, 56, 4,  2, 256, true, 2, 12544, 14, 56>
        <<<dim3(56, 16), 256, 0, stream>>>(h3, nullptr, d4w, d4b, pst3, g3w, g3b, h4, pst4);

    // fused head: final convT (GN-on-read of h4) + bilateral + tanh
    final_bilateral<<<dim3(14, 14, 16), 256, 0, stream>>>(h4, fw, fb, pst4, g4w, g4b, x, out);
}

// Round 11
// 234.135 us; speedup vs baseline: 1.0708x; 1.0241x over previous
//
#include <hip/hip_runtime.h>
#include <math.h>

#define PI_F 3.14159265358979323846f

// ================= SIFT block bodies (device, inlined into sift_all) =================
// bins planes padded to NPIX+1: pooling-read banks become (o + px*8) mod 32 ->
// 16 distinct banks -> 4-way conflict instead of 16-way.
template<int PS, int K>
__device__ __forceinline__
void sift_block(const float* __restrict__ x, float* __restrict__ out,
                int n, float* lds)
{
    constexpr int NT = 256;
    constexpr int NPIX = PS*PS;
    constexpr int NPIXP = NPIX + 1;
    constexpr int BK = 2*(PS/5);
    constexpr int STRIDE = PS/4;
    constexpr int PAD = BK/4;
    constexpr float HALF = BK*0.5f;
    constexpr int NWAVE = NT/64;
    constexpr int ROWS = BK/2;

    float* patch = lds;                  // NPIX
    float* bins  = patch + NPIX;         // 8*NPIXP
    float* g1    = bins + 8*NPIXP;       // PS
    float* pool2 = g1 + PS;              // 128
    float* wred  = pool2 + 128;          // NWAVE
    float* gsum_s = wred + NWAVE;        // 1

    const int tid = threadIdx.x;
    const int b = n / (K*K);
    const int c = n % (K*K);
    const int ki = c / K;
    const int kj = c % K;

    const float* xb = x + (size_t)b*224*224;
    for (int idx = tid; idx < NPIX; idx += NT) {
        int i = idx / PS, j = idx - i*PS;
        patch[idx] = xb[(i*K + ki)*224 + (j*K + kj)];
    }
    if (tid < PS) {
        const float sigma = (float)PS * 0.70710678118654752440f;
        float xv = (float)tid - (PS-1)*0.5f;
        float t = xv / sigma;
        g1[tid] = expf(-0.5f*t*t);
    }
    for (int idx = tid; idx < 8*NPIXP; idx += NT) bins[idx] = 0.f;
    __syncthreads();
    if (tid == 0) {
        float s = 0.f;
        for (int i = 0; i < PS; i++) s += g1[i];
        gsum_s[0] = s;
    }
    __syncthreads();
    const float ginv = 1.0f / (gsum_s[0]*gsum_s[0]);

    for (int idx = tid; idx < NPIX; idx += NT) {
        int i = idx / PS, j = idx - i*PS;
        int jm = j > 0 ? j-1 : 0, jp = j < PS-1 ? j+1 : PS-1;
        int im = i > 0 ? i-1 : 0, ip = i < PS-1 ? i+1 : PS-1;
        float gx = 0.5f*(patch[i*PS+jp] - patch[i*PS+jm]);
        float gy = 0.5f*(patch[ip*PS+j] - patch[im*PS+j]);
        float mag = sqrtf(gx*gx + gy*gy + 1e-10f) * (g1[i]*g1[j]*ginv);
        float ori = atan2f(gy, gx + 1e-10f) + 2.f*PI_F;
        float obig = ori * (8.f/(2.f*PI_F));
        float bo0f = floorf(obig);
        float w1 = obig - bo0f;
        int bo0 = ((int)bo0f) & 7;
        int bo1 = (bo0 + 1) & 7;
        bins[bo0*NPIXP + idx] = (1.f - w1)*mag;
        bins[bo1*NPIXP + idx] = w1*mag;
    }
    __syncthreads();

    // Triangular pooling, split across 2 thread halves
    float pacc = 0.f;
    const int t = tid & 127;
    const int half = tid >> 7;
    {
        int o = t >> 4;
        int py = (t >> 2) & 3;
        int px = t & 3;
        int sy = py*STRIDE - PAD;
        int sx = px*STRIDE - PAD;
        const float* bo = bins + o*NPIXP;
        for (int dr = 0; dr < ROWS; dr++) {
            int di = half*ROWS + dr;
            int i = sy + di;
            if (i < 0 || i >= PS) continue;
            float wi = HALF - fabsf((float)di + 0.5f - HALF);
            for (int dj = 0; dj < BK; dj++) {
                int j = sx + dj;
                if (j < 0 || j >= PS) continue;
                float wj = HALF - fabsf((float)dj + 0.5f - HALF);
                pacc += bo[i*PS + j] * (wi*wj);
            }
        }
    }
    if (half == 1) pool2[t] = pacc;
    __syncthreads();
    float d = 0.f;
    if (tid < 128) {
        d = (pacc + pool2[tid]) * (1.0f/(HALF*HALF));
    }

    const int wv = tid >> 6;
    const int ln = tid & 63;

    float v = d*d;
    #pragma unroll
    for (int off = 32; off > 0; off >>= 1) v += __shfl_down(v, off);
    if (ln == 0) wred[wv] = v;
    __syncthreads();
    float nrm = 0.f;
    #pragma unroll
    for (int w2 = 0; w2 < NWAVE; w2++) nrm += wred[w2];
    nrm = sqrtf(nrm);
    __syncthreads();
    d = d / fmaxf(nrm, 1e-12f);
    d = fminf(fmaxf(d, 0.f), 0.2f);

    v = d*d;
    #pragma unroll
    for (int off = 32; off > 0; off >>= 1) v += __shfl_down(v, off);
    if (ln == 0) wred[wv] = v;
    __syncthreads();
    nrm = 0.f;
    #pragma unroll
    for (int w2 = 0; w2 < NWAVE; w2++) nrm += wred[w2];
    nrm = sqrtf(nrm);
    __syncthreads();
    d = d / fmaxf(nrm, 1e-12f);

    v = d;   // d >= 0 -> sum == sum(|d|)
    #pragma unroll
    for (int off = 32; off > 0; off >>= 1) v += __shfl_down(v, off);
    if (ln == 0) wred[wv] = v;
    __syncthreads();
    float ssum = 0.f;
    #pragma unroll
    for (int w2 = 0; w2 < NWAVE; w2++) ssum += wred[w2];
    d = sqrtf(d / fmaxf(ssum, 1e-12f) + 1e-10f);

    if (tid < 128) out[(size_t)n*128 + tid] = d;
}

// PS=8 (K=28): one wave per patch, register-only
__device__ __forceinline__
void sift8_block(const float* __restrict__ x, float* __restrict__ out, int bid)
{
    const int tid = threadIdx.x;
    const int l = tid & 63;
    const int wv = tid >> 6;
    const int n = bid*4 + wv;
    const int b = n / 784;
    const int c = n % 784;
    const int ki = c / 28, kj = c % 28;
    const int i = l >> 3, j = l & 7;

    const float* xb = x + (size_t)b*50176;
    float v = xb[(i*28 + ki)*224 + (j*28 + kj)];

    int lL = (j > 0) ? l-1 : l;
    int lR = (j < 7) ? l+1 : l;
    int lU = (i > 0) ? l-8 : l;
    int lD = (i < 7) ? l+8 : l;
    float pL = __shfl(v, lL);
    float pR = __shfl(v, lR);
    float pU = __shfl(v, lU);
    float pD = __shfl(v, lD);
    float gx = 0.5f*(pR - pL);
    float gy = 0.5f*(pD - pU);

    float ti = ((float)i - 3.5f) * (1.f/5.65685424949238f);
    float tj = ((float)j - 3.5f) * (1.f/5.65685424949238f);
    float wsp = __expf(-0.5f*(ti*ti + tj*tj));
    float mag = sqrtf(gx*gx + gy*gy + 1e-10f) * wsp;
    float ori = atan2f(gy, gx + 1e-10f) + 2.f*PI_F;
    float obig = ori * (8.f/(2.f*PI_F));
    float bo0f = floorf(obig);
    float w1 = obig - bo0f;
    int bo0 = ((int)bo0f) & 7;
    int bo1 = (bo0 + 1) & 7;
    float c0 = (1.f - w1)*mag;
    float c1 = w1*mag;

    const int t = ((i & 1) << 1) | (j & 1);
    float d0 = 0.f, d1 = 0.f;
    #pragma unroll
    for (int o = 0; o < 8; o++) {
        float val = (bo0 == o ? c0 : 0.f) + (bo1 == o ? c1 : 0.f);
        val += __shfl_xor(val, 1);
        val += __shfl_xor(val, 8);
        if (o == 2*t)     d0 = val;
        if (o == 2*t + 1) d1 = val;
    }

    float s = d0*d0 + d1*d1;
    #pragma unroll
    for (int off = 32; off > 0; off >>= 1) s += __shfl_xor(s, off);
    float nrm = fmaxf(sqrtf(s), 1e-12f);
    d0 /= nrm; d1 /= nrm;
    d0 = fminf(fmaxf(d0, 0.f), 0.2f);
    d1 = fminf(fmaxf(d1, 0.f), 0.2f);
    s = d0*d0 + d1*d1;
    #pragma unroll
    for (int off = 32; off > 0; off >>= 1) s += __shfl_xor(s, off);
    nrm = fmaxf(sqrtf(s), 1e-12f);
    d0 /= nrm; d1 /= nrm;
    s = d0 + d1;
    #pragma unroll
    for (int off = 32; off > 0; off >>= 1) s += __shfl_xor(s, off);
    s = fmaxf(s, 1e-12f);
    d0 = sqrtf(d0/s + 1e-10f);
    d1 = sqrtf(d1/s + 1e-10f);

    int cell = (i >> 1)*4 + (j >> 1);
    float* ob = out + (size_t)n*128 + cell;
    ob[(2*t)*16]     = d0;
    ob[(2*t + 1)*16] = d1;
}

// ============ ONE dispatch for all three SIFT scales ============
__global__ __launch_bounds__(256)
void sift_all(const float* __restrict__ x, float* __restrict__ s7,
              float* __restrict__ s14, float* __restrict__ s28)
{
    __shared__ float lds[9408];   // PS=32 needs 9389 fl; PS=16 needs 2461 fl
    const int bid = blockIdx.x;
    if (bid < 784) {
        sift_block<32, 7>(x, s7, bid, lds);
    } else if (bid < 3920) {
        sift_block<16, 14>(x, s14, bid - 784, lds);
    } else {
        sift8_block(x, s28, bid - 3920);
    }
}

// ================= conv1x1 block body (device) =================
template<int CO, int S>
__device__ __forceinline__
void conv1x1_block(const float* __restrict__ in, const float* __restrict__ w,
                   const float* __restrict__ bias, float* __restrict__ out,
                   int bid, float* wt)
{
    const int tid = threadIdx.x;
    for (int i = tid; i < 128*CO; i += 256) {
        int c = i / CO, co = i - c*CO;
        wt[i] = w[co*128 + c];       // transposed: wt[c*CO+co]
    }
    __syncthreads();
    int idx = bid*256 + tid;         // 16*(CO/4)*S threads exactly
    int s = idx % S; int r = idx / S;
    int co4 = r % (CO/4); int b = r / (CO/4);
    int co = co4*4;
    const float* ib = in + (size_t)b*128*S + s;
    float acc0 = bias[co], acc1 = bias[co+1], acc2 = bias[co+2], acc3 = bias[co+3];
    #pragma unroll 8
    for (int c = 0; c < 128; c++) {
        float v = ib[c*S];
        const float4 wv = *(const float4*)&wt[c*CO + co];
        acc0 += v*wv.x; acc1 += v*wv.y; acc2 += v*wv.z; acc3 += v*wv.w;
    }
    float* ob = out + ((size_t)b*CO + co)*S + s;
    ob[0] = acc0; ob[S] = acc1; ob[2*S] = acc2; ob[3*S] = acc3;
}

// ================= L1 convT block body (device; CIN=128->32, 7->14, GN(8)) =================
__device__ __forceinline__
void convt_l1_block(const float* __restrict__ in0, const float* __restrict__ w,
                    const float* __restrict__ bias,
                    float* __restrict__ out, float2* __restrict__ pst_out,
                    int by, float* lds)
{
    constexpr int CIN = 128, COUT = 32, HIN = 7, NCH = 4, NT = 256;
    constexpr int H0 = 14, SP = 196, HIN2 = 49;
    constexpr int NR = 9, WIN = 9, TILE = CIN*NR*WIN;      // 10368
    constexpr int WSTRIDE = CIN*NCH*4 + 4;                 // 2052

    float* tile  = lds;                  // 10368
    float* wl2   = tile + TILE;          // 8208
    float* wpart = wl2 + 4*WSTRIDE;      // 8 (4 waves x {sum,sq})

    const int tid = threadIdx.x;
    const int b  = by >> 3;
    const int cb = by & 7;
    const int c0 = cb*NCH;

    for (int idx = tid; idx < 4*CIN*NCH*4; idx += NT) {
        int k = idx & 3;
        int t2 = idx >> 2;
        int j = t2 % NCH; t2 /= NCH;
        int ci = t2 % CIN;
        int pq = t2 / CIN;
        int pA = pq >> 1, qA = pq & 1;
        int dy = pA + 2*(k>>1), dx = qA + 2*(k&1);
        wl2[pq*WSTRIDE + (ci*NCH + j)*4 + k] = w[(ci*COUT + c0 + j)*16 + dy*4 + dx];
    }
    const float* i0 = in0 + (size_t)b*CIN*HIN2;
    for (int idx = tid; idx < TILE; idx += NT) {
        int c = idx % WIN;
        int t2 = idx / WIN;
        int r = t2 % NR;
        int ci = t2 / NR;
        int iy = r - 1, ix = c - 1;
        float v = 0.f;
        if (iy >= 0 && iy < HIN && ix >= 0 && ix < HIN)
            v = i0[ci*HIN2 + iy*HIN + ix];
        tile[idx] = v;
    }
    __syncthreads();

    float acc[NCH];
    #pragma unroll
    for (int j = 0; j < NCH; j++) acc[j] = 0.f;

    const bool active = tid < SP;
    if (active) {
        int oy = tid / H0, ox = tid % H0;
        int pA = (oy+1)&1, qA = (ox+1)&1;
        int iyA = (oy+1-pA)>>1, ixA = (ox+1-qA)>>1;
        int toff = (iyA+1)*WIN + (ixA+1);
        const float* wbase = wl2 + (pA*2+qA)*WSTRIDE;

        #pragma unroll
        for (int j = 0; j < NCH; j++) acc[j] = bias[c0 + j];

        #pragma unroll 4
        for (int ci = 0; ci < CIN; ci++) {
            const float* tp = tile + ci*(NR*WIN) + toff;
            float l0 = tp[0];
            float l1 = tp[-1];
            float l2 = tp[-WIN];
            float l3 = tp[-WIN-1];
            const float* wr = wbase + ci*NCH*4;
            #pragma unroll
            for (int j = 0; j < NCH; j++) {
                const float4 wv = *(const float4*)(wr + j*4);
                acc[j] += l0*wv.x + l1*wv.y + l2*wv.z + l3*wv.w;
            }
        }
        float* ob = out + ((size_t)b*COUT + c0)*SP + tid;
        #pragma unroll
        for (int j = 0; j < NCH; j++) ob[j*SP] = acc[j];
    }

    const int wv = tid >> 6;
    const int ln = tid & 63;
    float ps = 0.f, pq2 = 0.f;
    #pragma unroll
    for (int j = 0; j < NCH; j++) {
        float v = active ? acc[j] : 0.f;
        ps += v; pq2 += v*v;
    }
    #pragma unroll
    for (int off = 32; off > 0; off >>= 1) {
        ps  += __shfl_down(ps,  off);
        pq2 += __shfl_down(pq2, off);
    }
    if (ln == 0) { wpart[wv*2] = ps; wpart[wv*2+1] = pq2; }
    __syncthreads();
    if (tid == 0) {
        float s0 = wpart[0]+wpart[2]+wpart[4]+wpart[6];
        float s1 = wpart[1]+wpart[3]+wpart[5]+wpart[7];
        pst_out[(size_t)b*8 + cb] = make_float2(s0, s1);   // NBLK_OUT=1
    }
}

// ============ ONE dispatch: both skip conv1x1s + L1 convT (independent) ============
__global__ __launch_bounds__(256)
void skip_l1(const float* __restrict__ s14, const float* __restrict__ s28,
             const float* __restrict__ s1w, const float* __restrict__ s1b,
             const float* __restrict__ s2w, const float* __restrict__ s2b,
             const float* __restrict__ s7,  const float* __restrict__ d1w,
             const float* __restrict__ d1b,
             float* __restrict__ sk1, float* __restrict__ sk2,
             float* __restrict__ h1, float2* __restrict__ pst1)
{
    __shared__ float lds[18584];   // max(conv1x1 4096, L1 tile 10368+8208+8)
    const int bid = blockIdx.x;
    if (bid < 98)       conv1x1_block<32, 196>(s14, s1w, s1b, sk1, bid, lds);
    else if (bid < 294) conv1x1_block<16, 784>(s28, s2w, s2b, sk2, bid - 98, lds);
    else                convt_l1_block(s7, d1w, d1b, h1, pst1, bid - 294, lds);
}

// ====== ConvTranspose2d(k4,s2,p1) via LDS tile [+GN-on-read] -> partial GN stats ======
template<int CIN0, int CIN1, int COUT, int G, int HIN, int NCH, int RT, int NT,
         bool FUSE, int GIN, int NGIN, int NBLK_IN, int NBLK_OUT>
__global__ __launch_bounds__(NT)
void convt_tiled(const float* __restrict__ in0, const float* __restrict__ in1,
                 const float* __restrict__ w, const float* __restrict__ bias,
                 const float2* __restrict__ pst_in,
                 const float* __restrict__ gnw, const float* __restrict__ gnb,
                 float* __restrict__ out, float2* __restrict__ pst_out)
{
    constexpr int CIN = CIN0 + CIN1;
    constexpr int CG = COUT / G;
    constexpr int NGRP = NCH / CG;
    constexpr int CB = COUT / NCH;
    constexpr int H0 = 2*HIN;
    constexpr int SP = H0*H0;
    constexpr int HIN2 = HIN*HIN;
    constexpr int NR = RT/2 + 2;
    constexpr int WIN = HIN + 2;
    constexpr int TILE = CIN*NR*WIN;
    constexpr int WSTRIDE = CIN*NCH*4 + 4;
    constexpr int NPOS = RT*H0;
    constexpr int NWAVE = NT/64;

    __shared__ float tile[TILE];
    __shared__ float wl2[4*WSTRIDE];
    __shared__ float a_s[CIN0];
    __shared__ float b_s[CIN0];
    __shared__ float wpart[NWAVE][NGRP][2];

    const int tid = threadIdx.x;
    const int by = blockIdx.y;
    const int bx = blockIdx.x;
    const int b  = by / CB;
    const int cb = by - b*CB;
    const int c0 = cb*NCH;
    const int g0 = c0 / CG;
    const int r0 = bx * RT;
    const int row0 = r0/2 - 1;

    if constexpr (FUSE) {
        if (tid < CIN0) {
            int gi = tid / (CIN0/GIN);
            float s0 = 0.f, s1 = 0.f;
            for (int k = 0; k < NBLK_IN; k++) {
                float2 p = pst_in[((size_t)b*GIN + gi)*NBLK_IN + k];
                s0 += p.x; s1 += p.y;
            }
            float mean = s0 * (1.f/NGIN);
            float var  = s1 * (1.f/NGIN) - mean*mean;
            float inv  = rsqrtf(var + 1e-5f);
            float a = inv * gnw[tid];
            a_s[tid] = a;
            b_s[tid] = gnb[tid] - mean*a;
        }
        __syncthreads();
    }

    for (int idx = tid; idx < 4*CIN*NCH*4; idx += NT) {
        int k = idx & 3;
        int t2 = idx >> 2;
        int j = t2 % NCH; t2 /= NCH;
        int ci = t2 % CIN;
        int pq = t2 / CIN;
        int pA = pq >> 1, qA = pq & 1;
        int dy = pA + 2*(k>>1), dx = qA + 2*(k&1);
        wl2[pq*WSTRIDE + (ci*NCH + j)*4 + k] = w[(ci*COUT + c0 + j)*16 + dy*4 + dx];
    }

    const float* i0 = in0 + (size_t)b*CIN0*HIN2;
    for (int idx = tid; idx < TILE; idx += NT) {
        int c = idx % WIN;
        int t2 = idx / WIN;
        int r = t2 % NR;
        int ci = t2 / NR;
        int iy = row0 + r, ix = c - 1;
        float v = 0.f;
        if (iy >= 0 && iy < HIN && ix >= 0 && ix < HIN) {
            if (CIN1 == 0 || ci < CIN0) {
                v = i0[ci*HIN2 + iy*HIN + ix];
                if constexpr (FUSE) v = fmaxf(v*a_s[ci] + b_s[ci], 0.f);
            } else {
                v = in1[((size_t)b*CIN1 + (ci-CIN0))*HIN2 + iy*HIN + ix];
            }
        }
        tile[idx] = v;
    }
    __syncthreads();

    float acc[NCH];
    #pragma unroll
    for (int j = 0; j < NCH; j++) acc[j] = 0.f;

    const bool active = tid < NPOS;
    if (active) {
        int oy = r0 + tid / H0, ox = tid % H0;
        int pA = (oy+1)&1, qA = (ox+1)&1;
        int iyA = (oy+1-pA)>>1, ixA = (ox+1-qA)>>1;
        int rA = iyA - row0;
        int cA = ixA + 1;
        int toff = rA*WIN + cA;
        const float* wbase = wl2 + (pA*2+qA)*WSTRIDE;

        #pragma unroll
        for (int j = 0; j < NCH; j++) acc[j] = bias[c0 + j];

        #pragma unroll 4
        for (int ci = 0; ci < CIN; ci++) {
            const float* tp = tile + ci*(NR*WIN) + toff;
            float l0 = tp[0];
            float l1 = tp[-1];
            float l2 = tp[-WIN];
            float l3 = tp[-WIN-1];
            const float* wr = wbase + ci*NCH*4;
            #pragma unroll
            for (int j = 0; j < NCH; j++) {
                const float4 wv = *(const float4*)(wr + j*4);
                acc[j] += l0*wv.x + l1*wv.y + l2*wv.z + l3*wv.w;
            }
        }
        float* ob = out + ((size_t)b*COUT + c0)*SP + r0*H0 + tid;
        #pragma unroll
        for (int j = 0; j < NCH; j++) ob[j*SP] = acc[j];
    }

    const int wv = tid >> 6;
    const int ln = tid & 63;
    #pragma unroll
    for (int grp = 0; grp < NGRP; grp++) {
        float ps = 0.f, pq2 = 0.f;
        #pragma unroll
        for (int j = 0; j < CG; j++) {
            float v = active ? acc[grp*CG + j] : 0.f;
            ps += v; pq2 += v*v;
        }
        #pragma unroll
        for (int off = 32; off > 0; off >>= 1) {
            ps  += __shfl_down(ps,  off);
            pq2 += __shfl_down(pq2, off);
        }
        if (ln == 0) { wpart[wv][grp][0] = ps; wpart[wv][grp][1] = pq2; }
    }
    __syncthreads();
    if (tid < NGRP) {
        float s0 = 0.f, s1 = 0.f;
        #pragma unroll
        for (int w2 = 0; w2 < NWAVE; w2++) { s0 += wpart[w2][tid][0]; s1 += wpart[w2][tid][1]; }
        pst_out[((size_t)b*G + g0 + tid)*NBLK_OUT + bx] = make_float2(s0, s1);
    }
}

// ====== FUSED: final ConvTranspose2d(4->2, GN-on-read) + joint bilateral + tanh ======
__global__ __launch_bounds__(256)
void final_bilateral(const float* __restrict__ h4, const float* __restrict__ fw,
                     const float* __restrict__ fb, const float2* __restrict__ pst_in,
                     const float* __restrict__ gnw, const float* __restrict__ gnb,
                     const float* __restrict__ x, float* __restrict__ out)
{
    const float g[5] = {0.1200783f, 0.2338817f, 0.2920800f, 0.2338817f, 0.1200783f};
    __shared__ float xs[400], p0s[400], p1s[400];
    __shared__ float wl2[128];
    __shared__ float a_s[4], b_s[4], bl[2], mv[2];

    const int tid = threadIdx.x;
    const int b = blockIdx.z;
    const int ty0 = blockIdx.y*16;
    const int tx0 = blockIdx.x*16;
    const float* xb = x + (size_t)b*50176;

    if (tid < 128) {
        int k = tid & 3;
        int t = tid >> 2;
        int co = t & 1; t >>= 1;
        int ci = t & 3;
        int pq = t >> 2;
        int pA = pq >> 1, qA = pq & 1;
        int dy = pA + 2*(k>>1), dx = qA + 2*(k&1);
        wl2[tid] = fw[(ci*2 + co)*16 + dy*4 + dx];
    }
    if (tid < 2) bl[tid] = fb[tid];
    if (tid >= 192) {
        int k0 = tid - 192;
        float s0 = 0.f, s1 = 0.f;
        if (k0 < 56) {
            float2 p = pst_in[(size_t)b*56 + k0];
            s0 = p.x; s1 = p.y;
        }
        #pragma unroll
        for (int off = 32; off > 0; off >>= 1) {
            s0 += __shfl_down(s0, off);
            s1 += __shfl_down(s1, off);
        }
        if (k0 == 0) {
            float mean = s0 * (1.f/50176.f);
            float var  = s1 * (1.f/50176.f) - mean*mean;
            mv[0] = mean;
            mv[1] = rsqrtf(var + 1e-5f);
        }
    }
    __syncthreads();
    if (tid < 4) {
        float a = mv[1] * gnw[tid];
        a_s[tid] = a;
        b_s[tid] = gnb[tid] - mv[0]*a;
    }
    __syncthreads();

    const float* ib = h4 + (size_t)b*4*12544;
    for (int idx = tid; idx < 400; idx += 256) {
        int r = idx / 20, cc = idx - r*20;
        int oy = ty0 - 2 + r;  oy = oy < 0 ? -oy : (oy > 223 ? 446 - oy : oy);
        int ox = tx0 - 2 + cc; ox = ox < 0 ? -ox : (ox > 223 ? 446 - ox : ox);
        xs[idx] = xb[oy*224 + ox];

        int pA = (oy+1)&1, iyA = (oy+1-pA)>>1, iyB = iyA-1;
        int qA = (ox+1)&1, ixA = (ox+1-qA)>>1, ixB = ixA-1;
        float mYA = (iyA < 112) ? 1.f : 0.f;
        float mYB = (iyB >= 0)  ? 1.f : 0.f;
        float mXA = (ixA < 112) ? 1.f : 0.f;
        float mXB = (ixB >= 0)  ? 1.f : 0.f;
        float m0 = mYA*mXA, m1 = mYA*mXB, m2 = mYB*mXA, m3 = mYB*mXB;
        int iyAc = min(iyA, 111), iyBc = max(iyB, 0);
        int ixAc = min(ixA, 111), ixBc = max(ixB, 0);
        int oAA = iyAc*112 + ixAc, oAB = iyAc*112 + ixBc;
        int oBA = iyBc*112 + ixAc, oBB = iyBc*112 + ixBc;
        const float* wbase = wl2 + (pA*2+qA)*32;

        float acc0 = bl[0], acc1 = bl[1];
        #pragma unroll
        for (int ci = 0; ci < 4; ci++) {
            const float* ip = ib + ci*12544;
            float a = a_s[ci], bb = b_s[ci];
            float l0 = fmaxf(ip[oAA]*a + bb, 0.f);
            float l1 = fmaxf(ip[oAB]*a + bb, 0.f);
            float l2 = fmaxf(ip[oBA]*a + bb, 0.f);
            float l3 = fmaxf(ip[oBB]*a + bb, 0.f);
            float t0 = l0*m0, t1 = l1*m1, t2 = l2*m2, t3 = l3*m3;
            const float4 w0 = *(const float4*)(wbase + ci*8);
            const float4 w1 = *(const float4*)(wbase + ci*8 + 4);
            acc0 += t0*w0.x + t1*w0.y + t2*w0.z + t3*w0.w;
            acc1 += t0*w1.x + t1*w1.y + t2*w1.z + t3*w1.w;
        }
        p0s[idx] = acc0;
        p1s[idx] = acc1;
    }
    __syncthreads();

    int ly = tid >> 4, lx = tid & 15;
    int base = (ly+2)*20 + (lx+2);
    float center = xs[base];
    float wsum = 0.f, a0 = 0.f, a1 = 0.f;
    #pragma unroll
    for (int di = -2; di <= 2; di++){
        #pragma unroll
        for (int dj = -2; dj <= 2; dj++){
            int o = base + di*20 + dj;
            float dg = xs[o] - center;
            float wgt = g[di+2]*g[dj+2]*__expf(-200.f*dg*dg);
            wsum += wgt;
            a0 += wgt * p0s[o];
            a1 += wgt * p1s[o];
        }
    }
    float inv = 1.0f / wsum;
    int s = (ty0 + ly)*224 + (tx0 + lx);
    out[(size_t)(b*2)*50176 + s]     = tanhf(a0*inv)*0.436f;
    out[(size_t)(b*2+1)*50176 + s]   = tanhf(a1*inv)*0.615f;
}

// ======================= launch =======================
extern "C" void kernel_launch(void* const* d_in, const int* in_sizes, int n_in,
                              void* d_out, int out_size, void* d_ws, size_t ws_size,
                              hipStream_t stream) {
    (void)in_sizes; (void)n_in; (void)out_size; (void)ws_size;
    const float* x   = (const float*)d_in[0];
    const float* d1w = (const float*)d_in[1];
    const float* d1b = (const float*)d_in[2];
    const float* g1w = (const float*)d_in[3];
    const float* g1b = (const float*)d_in[4];
    const float* s1w = (const float*)d_in[5];
    const float* s1b = (const float*)d_in[6];
    const float* d2w = (const float*)d_in[7];
    const float* d2b = (const float*)d_in[8];
    const float* g2w = (const float*)d_in[9];
    const float* g2b = (const float*)d_in[10];
    const float* s2w = (const float*)d_in[11];
    const float* s2b = (const float*)d_in[12];
    const float* d3w = (const float*)d_in[13];
    const float* d3b = (const float*)d_in[14];
    const float* g3w = (const float*)d_in[15];
    const float* g3b = (const float*)d_in[16];
    const float* d4w = (const float*)d_in[17];
    const float* d4b = (const float*)d_in[18];
    const float* g4w = (const float*)d_in[19];
    const float* g4b = (const float*)d_in[20];
    const float* fw  = (const float*)d_in[21];
    const float* fb  = (const float*)d_in[22];
    float* out = (float*)d_out;

    float* ws  = (float*)d_ws;
    float* s7  = ws;                  // 16*128*49      = 100352
    float* s14 = s7  + 100352;        // 16*128*196     = 401408
    float* s28 = s14 + 401408;        // 16*128*784     = 1605632
    float* sk1 = s28 + 1605632;       // 16*32*196      = 100352
    float* sk2 = sk1 + 100352;        // 16*16*784      = 200704
    float* h1  = sk2 + 200704;        // 16*32*196      = 100352
    float* h2  = h1  + 100352;        // 16*16*784      = 200704
    float* h3  = h2  + 200704;        // 16*8*3136      = 401408
    float* h4  = h3  + 401408;        // 16*4*12544     = 802816
    float2* pst1 = (float2*)(h4 + 802816);     // 16*8  * 1  = 128 pairs
    float2* pst2 = pst1 + 128;                 // 16*4  * 7  = 448 pairs
    float2* pst3 = pst2 + 448;                 // 16*2  * 14 = 448 pairs
    float2* pst4 = pst3 + 448;                 // 16*1  * 56 = 896 pairs

    // d1: all SIFT scales (784 + 3136 + 3136 blocks)
    sift_all<<<7056, 256, 0, stream>>>(x, s7, s14, s28);

    // d2: both skip conv1x1s + L1 convT (independent after sift) — 98+196+128 blocks
    skip_l1<<<422, 256, 0, stream>>>(s14, s28, s1w, s1b, s2w, s2b,
                                     s7, d1w, d1b, sk1, sk2, h1, pst1);

    // d3: L2 convT(64->16, 14->28), GN(4)
    convt_tiled< 32,32, 16, 4, 14, 8,  4, 128, true, 8, 784, 1, 7>
        <<<dim3(7, 16*2), 128, 0, stream>>>(h1, sk1, d2w, d2b, pst1, g1w, g1b, h2, pst2);
    // d4: L3 convT(32->8, 28->56), GN(2)
    convt_tiled< 16,16,  8, 2, 28, 8,  4, 256, true, 4, 3136, 7, 14>
        <<<dim3(14, 16), 256, 0, stream>>>(h2, sk2, d3w, d3b, pst2, g2w, g2b, h3, pst3);
    // d5: L4 convT(8->4, 56->112), GN(1)
    convt_tiled<  8, 0,  4, 1, 56, 4,  2, 256, true, 2, 12544, 14, 56>
        <<<dim3(56, 16), 256, 0, stream>>>(h3, nullptr, d4w, d4b, pst3, g3w, g3b, h4, pst4);

    // d6: fused head (final convT GN-on-read + bilateral + tanh)
    final_bilateral<<<dim3(14, 14, 16), 256, 0, stream>>>(h4, fw, fb, pst4, g4w, g4b, x, out);
}

// Round 12
// 226.230 us; speedup vs baseline: 1.1082x; 1.0349x over previous
//
#include <hip/hip_runtime.h>
#include <math.h>

#define PI_F 3.14159265358979323846f

// ================= SIFT block body (PS=32 / PS=16): mag+obig planes only =================
// Uniform factors (1/gsum^2, 1/(HALF*HALF)) dropped — they cancel at the first L2
// normalize. Orientation binning is done inside the pooling taps (no 8-plane LDS).
// LDS: 3*NPIX + 256 floats (PS=32: 13.3 KB vs 37.6 KB before) -> 8 blocks/CU.
template<int PS, int K>
__device__ __forceinline__
void sift_block(const float* __restrict__ x, float* __restrict__ out,
                int n, float* lds)
{
    constexpr int NT = 256;
    constexpr int NPIX = PS*PS;
    constexpr int BK = 2*(PS/5);
    constexpr int STRIDE = PS/4;
    constexpr int PAD = BK/4;
    constexpr float HALF = BK*0.5f;
    constexpr int ROWS = BK/2;

    float* patch = lds;                  // NPIX
    float* magp  = patch + NPIX;         // NPIX
    float* obp   = magp + NPIX;          // NPIX
    float* pool2 = obp + NPIX;           // 256

    const int tid = threadIdx.x;
    const int b = n / (K*K);
    const int c = n % (K*K);
    const int ki = c / K;
    const int kj = c % K;

    const float* xb = x + (size_t)b*224*224;
    for (int idx = tid; idx < NPIX; idx += NT) {
        int i = idx / PS, j = idx - i*PS;
        patch[idx] = xb[(i*K + ki)*224 + (j*K + kj)];
    }
    __syncthreads();

    const float inv_sig = 1.0f / ((float)PS * 0.70710678118654752440f);
    for (int idx = tid; idx < NPIX; idx += NT) {
        int i = idx / PS, j = idx - i*PS;
        int jm = j > 0 ? j-1 : 0, jp = j < PS-1 ? j+1 : PS-1;
        int im = i > 0 ? i-1 : 0, ip = i < PS-1 ? i+1 : PS-1;
        float gx = 0.5f*(patch[i*PS+jp] - patch[i*PS+jm]);
        float gy = 0.5f*(patch[ip*PS+j] - patch[im*PS+j]);
        float ti = ((float)i - (PS-1)*0.5f) * inv_sig;
        float tj = ((float)j - (PS-1)*0.5f) * inv_sig;
        float wsp = __expf(-0.5f*(ti*ti + tj*tj));
        float mag = sqrtf(gx*gx + gy*gy + 1e-10f) * wsp;
        float ori = atan2f(gy, gx + 1e-10f) + 2.f*PI_F;
        magp[idx] = mag;
        obp[idx]  = ori * (8.f/(2.f*PI_F));   // (4, 12]
    }
    __syncthreads();

    // Triangular pooling with inline orientation binning; 2 row-halves x 128 elems
    float pacc = 0.f;
    {
        const int t = tid & 127;
        const int half = tid >> 7;
        const int o = t >> 4;
        const int py = (t >> 2) & 3;
        const int px = t & 3;
        const int sy = py*STRIDE - PAD;
        const int sx = px*STRIDE - PAD;
        for (int dr = 0; dr < ROWS; dr++) {
            int di = half*ROWS + dr;
            int i = sy + di;
            if (i < 0 || i >= PS) continue;
            float wi = HALF - fabsf((float)di + 0.5f - HALF);
            for (int dj = 0; dj < BK; dj++) {
                int j = sx + dj;
                if (j < 0 || j >= PS) continue;
                float wj = HALF - fabsf((float)dj + 0.5f - HALF);
                float m  = magp[i*PS + j];
                float ob = obp[i*PS + j];
                float bo0f = floorf(ob);
                float w1 = ob - bo0f;
                int bo0 = ((int)bo0f) & 7;
                int bo1 = (bo0 + 1) & 7;
                float ctr = (bo0 == o ? (1.f - w1) : 0.f) + (bo1 == o ? w1 : 0.f);
                pacc += ctr * m * (wi*wj);
            }
        }
    }
    pool2[tid] = pacc;
    __syncthreads();

    // wave 0 finishes: combine halves, butterfly normalize chain, store
    if (tid < 64) {
        float d0 = pool2[tid]      + pool2[tid + 128];   // desc[tid]
        float d1 = pool2[tid + 64] + pool2[tid + 192];   // desc[tid+64]

        float s = d0*d0 + d1*d1;
        #pragma unroll
        for (int off = 32; off > 0; off >>= 1) s += __shfl_xor(s, off);
        float nrm = fmaxf(sqrtf(s), 1e-12f);
        d0 /= nrm; d1 /= nrm;
        d0 = fminf(fmaxf(d0, 0.f), 0.2f);
        d1 = fminf(fmaxf(d1, 0.f), 0.2f);
        s = d0*d0 + d1*d1;
        #pragma unroll
        for (int off = 32; off > 0; off >>= 1) s += __shfl_xor(s, off);
        nrm = fmaxf(sqrtf(s), 1e-12f);
        d0 /= nrm; d1 /= nrm;
        s = d0 + d1;    // d >= 0
        #pragma unroll
        for (int off = 32; off > 0; off >>= 1) s += __shfl_xor(s, off);
        s = fmaxf(s, 1e-12f);
        d0 = sqrtf(d0/s + 1e-10f);
        d1 = sqrtf(d1/s + 1e-10f);

        out[(size_t)n*128 + tid]      = d0;
        out[(size_t)n*128 + 64 + tid] = d1;
    }
}

// PS=8 (K=28): one wave per patch, register-only
__device__ __forceinline__
void sift8_block(const float* __restrict__ x, float* __restrict__ out, int bid)
{
    const int tid = threadIdx.x;
    const int l = tid & 63;
    const int wv = tid >> 6;
    const int n = bid*4 + wv;
    const int b = n / 784;
    const int c = n % 784;
    const int ki = c / 28, kj = c % 28;
    const int i = l >> 3, j = l & 7;

    const float* xb = x + (size_t)b*50176;
    float v = xb[(i*28 + ki)*224 + (j*28 + kj)];

    int lL = (j > 0) ? l-1 : l;
    int lR = (j < 7) ? l+1 : l;
    int lU = (i > 0) ? l-8 : l;
    int lD = (i < 7) ? l+8 : l;
    float pL = __shfl(v, lL);
    float pR = __shfl(v, lR);
    float pU = __shfl(v, lU);
    float pD = __shfl(v, lD);
    float gx = 0.5f*(pR - pL);
    float gy = 0.5f*(pD - pU);

    float ti = ((float)i - 3.5f) * (1.f/5.65685424949238f);
    float tj = ((float)j - 3.5f) * (1.f/5.65685424949238f);
    float wsp = __expf(-0.5f*(ti*ti + tj*tj));
    float mag = sqrtf(gx*gx + gy*gy + 1e-10f) * wsp;
    float ori = atan2f(gy, gx + 1e-10f) + 2.f*PI_F;
    float obig = ori * (8.f/(2.f*PI_F));
    float bo0f = floorf(obig);
    float w1 = obig - bo0f;
    int bo0 = ((int)bo0f) & 7;
    int bo1 = (bo0 + 1) & 7;
    float c0 = (1.f - w1)*mag;
    float c1 = w1*mag;

    const int t = ((i & 1) << 1) | (j & 1);
    float d0 = 0.f, d1 = 0.f;
    #pragma unroll
    for (int o = 0; o < 8; o++) {
        float val = (bo0 == o ? c0 : 0.f) + (bo1 == o ? c1 : 0.f);
        val += __shfl_xor(val, 1);
        val += __shfl_xor(val, 8);
        if (o == 2*t)     d0 = val;
        if (o == 2*t + 1) d1 = val;
    }

    float s = d0*d0 + d1*d1;
    #pragma unroll
    for (int off = 32; off > 0; off >>= 1) s += __shfl_xor(s, off);
    float nrm = fmaxf(sqrtf(s), 1e-12f);
    d0 /= nrm; d1 /= nrm;
    d0 = fminf(fmaxf(d0, 0.f), 0.2f);
    d1 = fminf(fmaxf(d1, 0.f), 0.2f);
    s = d0*d0 + d1*d1;
    #pragma unroll
    for (int off = 32; off > 0; off >>= 1) s += __shfl_xor(s, off);
    nrm = fmaxf(sqrtf(s), 1e-12f);
    d0 /= nrm; d1 /= nrm;
    s = d0 + d1;
    #pragma unroll
    for (int off = 32; off > 0; off >>= 1) s += __shfl_xor(s, off);
    s = fmaxf(s, 1e-12f);
    d0 = sqrtf(d0/s + 1e-10f);
    d1 = sqrtf(d1/s + 1e-10f);

    int cell = (i >> 1)*4 + (j >> 1);
    float* ob = out + (size_t)n*128 + cell;
    ob[(2*t)*16]     = d0;
    ob[(2*t + 1)*16] = d1;
}

// ============ ONE dispatch for all three SIFT scales ============
__global__ __launch_bounds__(256)
void sift_all(const float* __restrict__ x, float* __restrict__ s7,
              float* __restrict__ s14, float* __restrict__ s28)
{
    __shared__ float lds[3328];   // PS=32: 3*1024+256; PS=16: 3*256+256
    const int bid = blockIdx.x;
    if (bid < 784) {
        sift_block<32, 7>(x, s7, bid, lds);
    } else if (bid < 3920) {
        sift_block<16, 14>(x, s14, bid - 784, lds);
    } else {
        sift8_block(x, s28, bid - 3920);
    }
}

// ================= conv1x1 block body (device) =================
template<int CO, int S>
__device__ __forceinline__
void conv1x1_block(const float* __restrict__ in, const float* __restrict__ w,
                   const float* __restrict__ bias, float* __restrict__ out,
                   int bid, float* wt)
{
    const int tid = threadIdx.x;
    for (int i = tid; i < 128*CO; i += 256) {
        int c = i / CO, co = i - c*CO;
        wt[i] = w[co*128 + c];       // transposed: wt[c*CO+co]
    }
    __syncthreads();
    int idx = bid*256 + tid;         // 16*(CO/4)*S threads exactly
    int s = idx % S; int r = idx / S;
    int co4 = r % (CO/4); int b = r / (CO/4);
    int co = co4*4;
    const float* ib = in + (size_t)b*128*S + s;
    float acc0 = bias[co], acc1 = bias[co+1], acc2 = bias[co+2], acc3 = bias[co+3];
    #pragma unroll 8
    for (int c = 0; c < 128; c++) {
        float v = ib[c*S];
        const float4 wv = *(const float4*)&wt[c*CO + co];
        acc0 += v*wv.x; acc1 += v*wv.y; acc2 += v*wv.z; acc3 += v*wv.w;
    }
    float* ob = out + ((size_t)b*CO + co)*S + s;
    ob[0] = acc0; ob[S] = acc1; ob[2*S] = acc2; ob[3*S] = acc3;
}

// ================= L1 convT block body (device; CIN=128->32, 7->14, GN(8)) =================
__device__ __forceinline__
void convt_l1_block(const float* __restrict__ in0, const float* __restrict__ w,
                    const float* __restrict__ bias,
                    float* __restrict__ out, float2* __restrict__ pst_out,
                    int by, float* lds)
{
    constexpr int CIN = 128, COUT = 32, HIN = 7, NCH = 4, NT = 256;
    constexpr int H0 = 14, SP = 196, HIN2 = 49;
    constexpr int NR = 9, WIN = 9, TILE = CIN*NR*WIN;      // 10368
    constexpr int WSTRIDE = CIN*NCH*4 + 4;                 // 2052

    float* tile  = lds;                  // 10368
    float* wl2   = tile + TILE;          // 8208
    float* wpart = wl2 + 4*WSTRIDE;      // 8

    const int tid = threadIdx.x;
    const int b  = by >> 3;
    const int cb = by & 7;
    const int c0 = cb*NCH;

    for (int idx = tid; idx < 4*CIN*NCH*4; idx += NT) {
        int k = idx & 3;
        int t2 = idx >> 2;
        int j = t2 % NCH; t2 /= NCH;
        int ci = t2 % CIN;
        int pq = t2 / CIN;
        int pA = pq >> 1, qA = pq & 1;
        int dy = pA + 2*(k>>1), dx = qA + 2*(k&1);
        wl2[pq*WSTRIDE + (ci*NCH + j)*4 + k] = w[(ci*COUT + c0 + j)*16 + dy*4 + dx];
    }
    const float* i0 = in0 + (size_t)b*CIN*HIN2;
    for (int idx = tid; idx < TILE; idx += NT) {
        int c = idx % WIN;
        int t2 = idx / WIN;
        int r = t2 % NR;
        int ci = t2 / NR;
        int iy = r - 1, ix = c - 1;
        float v = 0.f;
        if (iy >= 0 && iy < HIN && ix >= 0 && ix < HIN)
            v = i0[ci*HIN2 + iy*HIN + ix];
        tile[idx] = v;
    }
    __syncthreads();

    float acc[NCH];
    #pragma unroll
    for (int j = 0; j < NCH; j++) acc[j] = 0.f;

    const bool active = tid < SP;
    if (active) {
        int oy = tid / H0, ox = tid % H0;
        int pA = (oy+1)&1, qA = (ox+1)&1;
        int iyA = (oy+1-pA)>>1, ixA = (ox+1-qA)>>1;
        int toff = (iyA+1)*WIN + (ixA+1);
        const float* wbase = wl2 + (pA*2+qA)*WSTRIDE;

        #pragma unroll
        for (int j = 0; j < NCH; j++) acc[j] = bias[c0 + j];

        #pragma unroll 4
        for (int ci = 0; ci < CIN; ci++) {
            const float* tp = tile + ci*(NR*WIN) + toff;
            float l0 = tp[0];
            float l1 = tp[-1];
            float l2 = tp[-WIN];
            float l3 = tp[-WIN-1];
            const float* wr = wbase + ci*NCH*4;
            #pragma unroll
            for (int j = 0; j < NCH; j++) {
                const float4 wv = *(const float4*)(wr + j*4);
                acc[j] += l0*wv.x + l1*wv.y + l2*wv.z + l3*wv.w;
            }
        }
        float* ob = out + ((size_t)b*COUT + c0)*SP + tid;
        #pragma unroll
        for (int j = 0; j < NCH; j++) ob[j*SP] = acc[j];
    }

    const int wv = tid >> 6;
    const int ln = tid & 63;
    float ps = 0.f, pq2 = 0.f;
    #pragma unroll
    for (int j = 0; j < NCH; j++) {
        float v = active ? acc[j] : 0.f;
        ps += v; pq2 += v*v;
    }
    #pragma unroll
    for (int off = 32; off > 0; off >>= 1) {
        ps  += __shfl_down(ps,  off);
        pq2 += __shfl_down(pq2, off);
    }
    if (ln == 0) { wpart[wv*2] = ps; wpart[wv*2+1] = pq2; }
    __syncthreads();
    if (tid == 0) {
        float s0 = wpart[0]+wpart[2]+wpart[4]+wpart[6];
        float s1 = wpart[1]+wpart[3]+wpart[5]+wpart[7];
        pst_out[(size_t)b*8 + cb] = make_float2(s0, s1);
    }
}

// ============ ONE dispatch: both skip conv1x1s + L1 convT (independent) ============
__global__ __launch_bounds__(256)
void skip_l1(const float* __restrict__ s14, const float* __restrict__ s28,
             const float* __restrict__ s1w, const float* __restrict__ s1b,
             const float* __restrict__ s2w, const float* __restrict__ s2b,
             const float* __restrict__ s7,  const float* __restrict__ d1w,
             const float* __restrict__ d1b,
             float* __restrict__ sk1, float* __restrict__ sk2,
             float* __restrict__ h1, float2* __restrict__ pst1)
{
    __shared__ float lds[18584];   // max(conv1x1 4096, L1 10368+8208+8)
    const int bid = blockIdx.x;
    if (bid < 98)       conv1x1_block<32, 196>(s14, s1w, s1b, sk1, bid, lds);
    else if (bid < 294) conv1x1_block<16, 784>(s28, s2w, s2b, sk2, bid - 98, lds);
    else                convt_l1_block(s7, d1w, d1b, h1, pst1, bid - 294, lds);
}

// ====== ConvTranspose2d(k4,s2,p1) via LDS tile [+GN-on-read] -> partial GN stats ======
template<int CIN0, int CIN1, int COUT, int G, int HIN, int NCH, int RT, int NT,
         bool FUSE, int GIN, int NGIN, int NBLK_IN, int NBLK_OUT>
__global__ __launch_bounds__(NT)
void convt_tiled(const float* __restrict__ in0, const float* __restrict__ in1,
                 const float* __restrict__ w, const float* __restrict__ bias,
                 const float2* __restrict__ pst_in,
                 const float* __restrict__ gnw, const float* __restrict__ gnb,
                 float* __restrict__ out, float2* __restrict__ pst_out)
{
    constexpr int CIN = CIN0 + CIN1;
    constexpr int CG = COUT / G;
    constexpr int NGRP = NCH / CG;
    constexpr int CB = COUT / NCH;
    constexpr int H0 = 2*HIN;
    constexpr int SP = H0*H0;
    constexpr int HIN2 = HIN*HIN;
    constexpr int NR = RT/2 + 2;
    constexpr int WIN = HIN + 2;
    constexpr int TILE = CIN*NR*WIN;
    constexpr int WSTRIDE = CIN*NCH*4 + 4;
    constexpr int NPOS = RT*H0;
    constexpr int NWAVE = NT/64;

    __shared__ float tile[TILE];
    __shared__ float wl2[4*WSTRIDE];
    __shared__ float a_s[CIN0];
    __shared__ float b_s[CIN0];
    __shared__ float wpart[NWAVE][NGRP][2];

    const int tid = threadIdx.x;
    const int by = blockIdx.y;
    const int bx = blockIdx.x;
    const int b  = by / CB;
    const int cb = by - b*CB;
    const int c0 = cb*NCH;
    const int g0 = c0 / CG;
    const int r0 = bx * RT;
    const int row0 = r0/2 - 1;

    if constexpr (FUSE) {
        if (tid < CIN0) {
            int gi = tid / (CIN0/GIN);
            float s0 = 0.f, s1 = 0.f;
            for (int k = 0; k < NBLK_IN; k++) {
                float2 p = pst_in[((size_t)b*GIN + gi)*NBLK_IN + k];
                s0 += p.x; s1 += p.y;
            }
            float mean = s0 * (1.f/NGIN);
            float var  = s1 * (1.f/NGIN) - mean*mean;
            float inv  = rsqrtf(var + 1e-5f);
            float a = inv * gnw[tid];
            a_s[tid] = a;
            b_s[tid] = gnb[tid] - mean*a;
        }
        __syncthreads();
    }

    for (int idx = tid; idx < 4*CIN*NCH*4; idx += NT) {
        int k = idx & 3;
        int t2 = idx >> 2;
        int j = t2 % NCH; t2 /= NCH;
        int ci = t2 % CIN;
        int pq = t2 / CIN;
        int pA = pq >> 1, qA = pq & 1;
        int dy = pA + 2*(k>>1), dx = qA + 2*(k&1);
        wl2[pq*WSTRIDE + (ci*NCH + j)*4 + k] = w[(ci*COUT + c0 + j)*16 + dy*4 + dx];
    }

    const float* i0 = in0 + (size_t)b*CIN0*HIN2;
    for (int idx = tid; idx < TILE; idx += NT) {
        int c = idx % WIN;
        int t2 = idx / WIN;
        int r = t2 % NR;
        int ci = t2 / NR;
        int iy = row0 + r, ix = c - 1;
        float v = 0.f;
        if (iy >= 0 && iy < HIN && ix >= 0 && ix < HIN) {
            if (CIN1 == 0 || ci < CIN0) {
                v = i0[ci*HIN2 + iy*HIN + ix];
                if constexpr (FUSE) v = fmaxf(v*a_s[ci] + b_s[ci], 0.f);
            } else {
                v = in1[((size_t)b*CIN1 + (ci-CIN0))*HIN2 + iy*HIN + ix];
            }
        }
        tile[idx] = v;
    }
    __syncthreads();

    float acc[NCH];
    #pragma unroll
    for (int j = 0; j < NCH; j++) acc[j] = 0.f;

    const bool active = tid < NPOS;
    if (active) {
        int oy = r0 + tid / H0, ox = tid % H0;
        int pA = (oy+1)&1, qA = (ox+1)&1;
        int iyA = (oy+1-pA)>>1, ixA = (ox+1-qA)>>1;
        int rA = iyA - row0;
        int cA = ixA + 1;
        int toff = rA*WIN + cA;
        const float* wbase = wl2 + (pA*2+qA)*WSTRIDE;

        #pragma unroll
        for (int j = 0; j < NCH; j++) acc[j] = bias[c0 + j];

        #pragma unroll 4
        for (int ci = 0; ci < CIN; ci++) {
            const float* tp = tile + ci*(NR*WIN) + toff;
            float l0 = tp[0];
            float l1 = tp[-1];
            float l2 = tp[-WIN];
            float l3 = tp[-WIN-1];
            const float* wr = wbase + ci*NCH*4;
            #pragma unroll
            for (int j = 0; j < NCH; j++) {
                const float4 wv = *(const float4*)(wr + j*4);
                acc[j] += l0*wv.x + l1*wv.y + l2*wv.z + l3*wv.w;
            }
        }
        float* ob = out + ((size_t)b*COUT + c0)*SP + r0*H0 + tid;
        #pragma unroll
        for (int j = 0; j < NCH; j++) ob[j*SP] = acc[j];
    }

    const int wv = tid >> 6;
    const int ln = tid & 63;
    #pragma unroll
    for (int grp = 0; grp < NGRP; grp++) {
        float ps = 0.f, pq2 = 0.f;
        #pragma unroll
        for (int j = 0; j < CG; j++) {
            float v = active ? acc[grp*CG + j] : 0.f;
            ps += v; pq2 += v*v;
        }
        #pragma unroll
        for (int off = 32; off > 0; off >>= 1) {
            ps  += __shfl_down(ps,  off);
            pq2 += __shfl_down(pq2, off);
        }
        if (ln == 0) { wpart[wv][grp][0] = ps; wpart[wv][grp][1] = pq2; }
    }
    __syncthreads();
    if (tid < NGRP) {
        float s0 = 0.f, s1 = 0.f;
        #pragma unroll
        for (int w2 = 0; w2 < NWAVE; w2++) { s0 += wpart[w2][tid][0]; s1 += wpart[w2][tid][1]; }
        pst_out[((size_t)b*G + g0 + tid)*NBLK_OUT + bx] = make_float2(s0, s1);
    }
}

// ====== FUSED: final ConvTranspose2d(4->2, GN-on-read) + joint bilateral + tanh ======
__global__ __launch_bounds__(256)
void final_bilateral(const float* __restrict__ h4, const float* __restrict__ fw,
                     const float* __restrict__ fb, const float2* __restrict__ pst_in,
                     const float* __restrict__ gnw, const float* __restrict__ gnb,
                     const float* __restrict__ x, float* __restrict__ out)
{
    const float g[5] = {0.1200783f, 0.2338817f, 0.2920800f, 0.2338817f, 0.1200783f};
    __shared__ float xs[400], p0s[400], p1s[400];
    __shared__ float wl2[128];
    __shared__ float a_s[4], b_s[4], bl[2], mv[2];

    const int tid = threadIdx.x;
    const int b = blockIdx.z;
    const int ty0 = blockIdx.y*16;
    const int tx0 = blockIdx.x*16;
    const float* xb = x + (size_t)b*50176;

    if (tid < 128) {
        int k = tid & 3;
        int t = tid >> 2;
        int co = t & 1; t >>= 1;
        int ci = t & 3;
        int pq = t >> 2;
        int pA = pq >> 1, qA = pq & 1;
        int dy = pA + 2*(k>>1), dx = qA + 2*(k&1);
        wl2[tid] = fw[(ci*2 + co)*16 + dy*4 + dx];
    }
    if (tid < 2) bl[tid] = fb[tid];
    if (tid >= 192) {
        int k0 = tid - 192;
        float s0 = 0.f, s1 = 0.f;
        if (k0 < 56) {
            float2 p = pst_in[(size_t)b*56 + k0];
            s0 = p.x; s1 = p.y;
        }
        #pragma unroll
        for (int off = 32; off > 0; off >>= 1) {
            s0 += __shfl_down(s0, off);
            s1 += __shfl_down(s1, off);
        }
        if (k0 == 0) {
            float mean = s0 * (1.f/50176.f);
            float var  = s1 * (1.f/50176.f) - mean*mean;
            mv[0] = mean;
            mv[1] = rsqrtf(var + 1e-5f);
        }
    }
    __syncthreads();
    if (tid < 4) {
        float a = mv[1] * gnw[tid];
        a_s[tid] = a;
        b_s[tid] = gnb[tid] - mv[0]*a;
    }
    __syncthreads();

    const float* ib = h4 + (size_t)b*4*12544;
    for (int idx = tid; idx < 400; idx += 256) {
        int r = idx / 20, cc = idx - r*20;
        int oy = ty0 - 2 + r;  oy = oy < 0 ? -oy : (oy > 223 ? 446 - oy : oy);
        int ox = tx0 - 2 + cc; ox = ox < 0 ? -ox : (ox > 223 ? 446 - ox : ox);
        xs[idx] = xb[oy*224 + ox];

        int pA = (oy+1)&1, iyA = (oy+1-pA)>>1, iyB = iyA-1;
        int qA = (ox+1)&1, ixA = (ox+1-qA)>>1, ixB = ixA-1;
        float mYA = (iyA < 112) ? 1.f : 0.f;
        float mYB = (iyB >= 0)  ? 1.f : 0.f;
        float mXA = (ixA < 112) ? 1.f : 0.f;
        float mXB = (ixB >= 0)  ? 1.f : 0.f;
        float m0 = mYA*mXA, m1 = mYA*mXB, m2 = mYB*mXA, m3 = mYB*mXB;
        int iyAc = min(iyA, 111), iyBc = max(iyB, 0);
        int ixAc = min(ixA, 111), ixBc = max(ixB, 0);
        int oAA = iyAc*112 + ixAc, oAB = iyAc*112 + ixBc;
        int oBA = iyBc*112 + ixAc, oBB = iyBc*112 + ixBc;
        const float* wbase = wl2 + (pA*2+qA)*32;

        float acc0 = bl[0], acc1 = bl[1];
        #pragma unroll
        for (int ci = 0; ci < 4; ci++) {
            const float* ip = ib + ci*12544;
            float a = a_s[ci], bb = b_s[ci];
            float l0 = fmaxf(ip[oAA]*a + bb, 0.f);
            float l1 = fmaxf(ip[oAB]*a + bb, 0.f);
            float l2 = fmaxf(ip[oBA]*a + bb, 0.f);
            float l3 = fmaxf(ip[oBB]*a + bb, 0.f);
            float t0 = l0*m0, t1 = l1*m1, t2 = l2*m2, t3 = l3*m3;
            const float4 w0 = *(const float4*)(wbase + ci*8);
            const float4 w1 = *(const float4*)(wbase + ci*8 + 4);
            acc0 += t0*w0.x + t1*w0.y + t2*w0.z + t3*w0.w;
            acc1 += t0*w1.x + t1*w1.y + t2*w1.z + t3*w1.w;
        }
        p0s[idx] = acc0;
        p1s[idx] = acc1;
    }
    __syncthreads();

    int ly = tid >> 4, lx = tid & 15;
    int base = (ly+2)*20 + (lx+2);
    float center = xs[base];
    float wsum = 0.f, a0 = 0.f, a1 = 0.f;
    #pragma unroll
    for (int di = -2; di <= 2; di++){
        #pragma unroll
        for (int dj = -2; dj <= 2; dj++){
            int o = base + di*20 + dj;
            float dg = xs[o] - center;
            float wgt = g[di+2]*g[dj+2]*__expf(-200.f*dg*dg);
            wsum += wgt;
            a0 += wgt * p0s[o];
            a1 += wgt * p1s[o];
        }
    }
    float inv = 1.0f / wsum;
    int s = (ty0 + ly)*224 + (tx0 + lx);
    out[(size_t)(b*2)*50176 + s]     = tanhf(a0*inv)*0.436f;
    out[(size_t)(b*2+1)*50176 + s]   = tanhf(a1*inv)*0.615f;
}

// ======================= launch =======================
extern "C" void kernel_launch(void* const* d_in, const int* in_sizes, int n_in,
                              void* d_out, int out_size, void* d_ws, size_t ws_size,
                              hipStream_t stream) {
    (void)in_sizes; (void)n_in; (void)out_size; (void)ws_size;
    const float* x   = (const float*)d_in[0];
    const float* d1w = (const float*)d_in[1];
    const float* d1b = (const float*)d_in[2];
    const float* g1w = (const float*)d_in[3];
    const float* g1b = (const float*)d_in[4];
    const float* s1w = (const float*)d_in[5];
    const float* s1b = (const float*)d_in[6];
    const float* d2w = (const float*)d_in[7];
    const float* d2b = (const float*)d_in[8];
    const float* g2w = (const float*)d_in[9];
    const float* g2b = (const float*)d_in[10];
    const float* s2w = (const float*)d_in[11];
    const float* s2b = (const float*)d_in[12];
    const float* d3w = (const float*)d_in[13];
    const float* d3b = (const float*)d_in[14];
    const float* g3w = (const float*)d_in[15];
    const float* g3b = (const float*)d_in[16];
    const float* d4w = (const float*)d_in[17];
    const float* d4b = (const float*)d_in[18];
    const float* g4w = (const float*)d_in[19];
    const float* g4b = (const float*)d_in[20];
    const float* fw  = (const float*)d_in[21];
    const float* fb  = (const float*)d_in[22];
    float* out = (float*)d_out;

    float* ws  = (float*)d_ws;
    float* s7  = ws;                  // 16*128*49      = 100352
    float* s14 = s7  + 100352;        // 16*128*196     = 401408
    float* s28 = s14 + 401408;        // 16*128*784     = 1605632
    float* sk1 = s28 + 1605632;       // 16*32*196      = 100352
    float* sk2 = sk1 + 100352;        // 16*16*784      = 200704
    float* h1  = sk2 + 200704;        // 16*32*196      = 100352
    float* h2  = h1  + 100352;        // 16*16*784      = 200704
    float* h3  = h2  + 200704;        // 16*8*3136      = 401408
    float* h4  = h3  + 401408;        // 16*4*12544     = 802816
    float2* pst1 = (float2*)(h4 + 802816);     // 16*8  * 1  = 128 pairs
    float2* pst2 = pst1 + 128;                 // 16*4  * 7  = 448 pairs
    float2* pst3 = pst2 + 448;                 // 16*2  * 14 = 448 pairs
    float2* pst4 = pst3 + 448;                 // 16*1  * 56 = 896 pairs

    // d1: all SIFT scales (784 + 3136 + 3136 blocks)
    sift_all<<<7056, 256, 0, stream>>>(x, s7, s14, s28);

    // d2: both skip conv1x1s + L1 convT — 98+196+128 blocks
    skip_l1<<<422, 256, 0, stream>>>(s14, s28, s1w, s1b, s2w, s2b,
                                     s7, d1w, d1b, sk1, sk2, h1, pst1);

    // d3: L2 convT(64->16, 14->28), GN(4)
    convt_tiled< 32,32, 16, 4, 14, 8,  4, 128, true, 8, 784, 1, 7>
        <<<dim3(7, 16*2), 128, 0, stream>>>(h1, sk1, d2w, d2b, pst1, g1w, g1b, h2, pst2);
    // d4: L3 convT(32->8, 28->56), GN(2)
    convt_tiled< 16,16,  8, 2, 28, 8,  4, 256, true, 4, 3136, 7, 14>
        <<<dim3(14, 16), 256, 0, stream>>>(h2, sk2, d3w, d3b, pst2, g2w, g2b, h3, pst3);
    // d5: L4 convT(8->4, 56->112), GN(1)
    convt_tiled<  8, 0,  4, 1, 56, 4,  2, 256, true, 2, 12544, 14, 56>
        <<<dim3(56, 16), 256, 0, stream>>>(h3, nullptr, d4w, d4b, pst3, g3w, g3b, h4, pst4);

    // d6: fused head (final convT GN-on-read + bilateral + tanh)
    final_bilateral<<<dim3(14, 14, 16), 256, 0, stream>>>(h4, fw, fb, pst4, g4w, g4b, x, out);
}

// Round 13
// 217.007 us; speedup vs baseline: 1.1553x; 1.0425x over previous
//
#include <hip/hip_runtime.h>
#include <math.h>

#define PI_F 3.14159265358979323846f

// ================= SIFT block body (PS=32 / PS=16) =================
// Planes: patch, c0 (=(1-w1)*mag), c1 (=w1*mag), bo0 (bin index as float).
// Pooling: 16 threads per (py,px) window, each scans BK*BK/16 taps once and
// accumulates all 8 orientation bins in registers; shfl_xor reduce over the
// 16-lane group. Uniform factors dropped (cancel at first L2 normalize).
template<int PS, int K>
__device__ __forceinline__
void sift_block(const float* __restrict__ x, float* __restrict__ out,
                int n, float* lds)
{
    constexpr int NT = 256;
    constexpr int NPIX = PS*PS;
    constexpr int BK = 2*(PS/5);
    constexpr int STRIDE = PS/4;
    constexpr int PAD = BK/4;
    constexpr float HALF = BK*0.5f;

    float* patch = lds;                  // NPIX
    float* c0p   = patch + NPIX;         // NPIX
    float* c1p   = c0p + NPIX;           // NPIX
    float* bo0p  = c1p + NPIX;           // NPIX
    float* pool2 = bo0p + NPIX;          // 128

    const int tid = threadIdx.x;
    const int b = n / (K*K);
    const int c = n % (K*K);
    const int ki = c / K;
    const int kj = c % K;

    const float* xb = x + (size_t)b*224*224;
    for (int idx = tid; idx < NPIX; idx += NT) {
        int i = idx / PS, j = idx - i*PS;
        patch[idx] = xb[(i*K + ki)*224 + (j*K + kj)];
    }
    __syncthreads();

    const float inv_sig = 1.0f / ((float)PS * 0.70710678118654752440f);
    for (int idx = tid; idx < NPIX; idx += NT) {
        int i = idx / PS, j = idx - i*PS;
        int jm = j > 0 ? j-1 : 0, jp = j < PS-1 ? j+1 : PS-1;
        int im = i > 0 ? i-1 : 0, ip = i < PS-1 ? i+1 : PS-1;
        float gx = 0.5f*(patch[i*PS+jp] - patch[i*PS+jm]);
        float gy = 0.5f*(patch[ip*PS+j] - patch[im*PS+j]);
        float ti = ((float)i - (PS-1)*0.5f) * inv_sig;
        float tj = ((float)j - (PS-1)*0.5f) * inv_sig;
        float wsp = __expf(-0.5f*(ti*ti + tj*tj));
        float mag = sqrtf(gx*gx + gy*gy + 1e-10f) * wsp;
        float ori = atan2f(gy, gx + 1e-10f) + 2.f*PI_F;
        float ob  = ori * (8.f/(2.f*PI_F));          // (4, 12]
        float bo0f = floorf(ob);
        float w1 = ob - bo0f;
        int bo0 = ((int)bo0f) & 7;
        c0p[idx]  = (1.f - w1)*mag;
        c1p[idx]  = w1*mag;
        bo0p[idx] = (float)bo0;
    }
    __syncthreads();

    // Pooling: win = tid>>4 (py=win>>2, px=win&3), sub = tid&15.
    {
        const int win = tid >> 4;
        const int sub = tid & 15;
        const int py = win >> 2;
        const int px = win & 3;
        const int sy = py*STRIDE - PAD;
        const int sx = px*STRIDE - PAD;
        float acc[8];
        #pragma unroll
        for (int o = 0; o < 8; o++) acc[o] = 0.f;

        for (int tap = sub; tap < BK*BK; tap += 16) {
            int di = tap / BK, dj = tap - di*BK;
            int i = sy + di, j = sx + dj;
            if (i < 0 || i >= PS || j < 0 || j >= PS) continue;
            float wgt = (HALF - fabsf((float)di + 0.5f - HALF)) *
                        (HALF - fabsf((float)dj + 0.5f - HALF));
            int idx = i*PS + j;
            float c0 = c0p[idx] * wgt;
            float c1 = c1p[idx] * wgt;
            float bo = bo0p[idx];
            #pragma unroll
            for (int o = 0; o < 8; o++) {
                float ctr = (bo == (float)o) ? c0 :
                            ((bo == (float)((o+7)&7)) ? c1 : 0.f);
                acc[o] += ctr;
            }
        }
        #pragma unroll
        for (int o = 0; o < 8; o++) {
            float v = acc[o];
            v += __shfl_xor(v, 1);
            v += __shfl_xor(v, 2);
            v += __shfl_xor(v, 4);
            v += __shfl_xor(v, 8);
            if (sub == 0) pool2[o*16 + win] = v;
        }
    }
    __syncthreads();

    // wave 0: butterfly normalize chain, store
    if (tid < 64) {
        float d0 = pool2[tid];
        float d1 = pool2[tid + 64];

        float s = d0*d0 + d1*d1;
        #pragma unroll
        for (int off = 32; off > 0; off >>= 1) s += __shfl_xor(s, off);
        float nrm = fmaxf(sqrtf(s), 1e-12f);
        d0 /= nrm; d1 /= nrm;
        d0 = fminf(fmaxf(d0, 0.f), 0.2f);
        d1 = fminf(fmaxf(d1, 0.f), 0.2f);
        s = d0*d0 + d1*d1;
        #pragma unroll
        for (int off = 32; off > 0; off >>= 1) s += __shfl_xor(s, off);
        nrm = fmaxf(sqrtf(s), 1e-12f);
        d0 /= nrm; d1 /= nrm;
        s = d0 + d1;    // d >= 0
        #pragma unroll
        for (int off = 32; off > 0; off >>= 1) s += __shfl_xor(s, off);
        s = fmaxf(s, 1e-12f);
        d0 = sqrtf(d0/s + 1e-10f);
        d1 = sqrtf(d1/s + 1e-10f);

        out[(size_t)n*128 + tid]      = d0;
        out[(size_t)n*128 + 64 + tid] = d1;
    }
}

// PS=8 (K=28): one wave per patch, register-only
__device__ __forceinline__
void sift8_block(const float* __restrict__ x, float* __restrict__ out, int bid)
{
    const int tid = threadIdx.x;
    const int l = tid & 63;
    const int wv = tid >> 6;
    const int n = bid*4 + wv;
    const int b = n / 784;
    const int c = n % 784;
    const int ki = c / 28, kj = c % 28;
    const int i = l >> 3, j = l & 7;

    const float* xb = x + (size_t)b*50176;
    float v = xb[(i*28 + ki)*224 + (j*28 + kj)];

    int lL = (j > 0) ? l-1 : l;
    int lR = (j < 7) ? l+1 : l;
    int lU = (i > 0) ? l-8 : l;
    int lD = (i < 7) ? l+8 : l;
    float pL = __shfl(v, lL);
    float pR = __shfl(v, lR);
    float pU = __shfl(v, lU);
    float pD = __shfl(v, lD);
    float gx = 0.5f*(pR - pL);
    float gy = 0.5f*(pD - pU);

    float ti = ((float)i - 3.5f) * (1.f/5.65685424949238f);
    float tj = ((float)j - 3.5f) * (1.f/5.65685424949238f);
    float wsp = __expf(-0.5f*(ti*ti + tj*tj));
    float mag = sqrtf(gx*gx + gy*gy + 1e-10f) * wsp;
    float ori = atan2f(gy, gx + 1e-10f) + 2.f*PI_F;
    float obig = ori * (8.f/(2.f*PI_F));
    float bo0f = floorf(obig);
    float w1 = obig - bo0f;
    int bo0 = ((int)bo0f) & 7;
    int bo1 = (bo0 + 1) & 7;
    float c0 = (1.f - w1)*mag;
    float c1 = w1*mag;

    const int t = ((i & 1) << 1) | (j & 1);
    float d0 = 0.f, d1 = 0.f;
    #pragma unroll
    for (int o = 0; o < 8; o++) {
        float val = (bo0 == o ? c0 : 0.f) + (bo1 == o ? c1 : 0.f);
        val += __shfl_xor(val, 1);
        val += __shfl_xor(val, 8);
        if (o == 2*t)     d0 = val;
        if (o == 2*t + 1) d1 = val;
    }

    float s = d0*d0 + d1*d1;
    #pragma unroll
    for (int off = 32; off > 0; off >>= 1) s += __shfl_xor(s, off);
    float nrm = fmaxf(sqrtf(s), 1e-12f);
    d0 /= nrm; d1 /= nrm;
    d0 = fminf(fmaxf(d0, 0.f), 0.2f);
    d1 = fminf(fmaxf(d1, 0.f), 0.2f);
    s = d0*d0 + d1*d1;
    #pragma unroll
    for (int off = 32; off > 0; off >>= 1) s += __shfl_xor(s, off);
    nrm = fmaxf(sqrtf(s), 1e-12f);
    d0 /= nrm; d1 /= nrm;
    s = d0 + d1;
    #pragma unroll
    for (int off = 32; off > 0; off >>= 1) s += __shfl_xor(s, off);
    s = fmaxf(s, 1e-12f);
    d0 = sqrtf(d0/s + 1e-10f);
    d1 = sqrtf(d1/s + 1e-10f);

    int cell = (i >> 1)*4 + (j >> 1);
    float* ob = out + (size_t)n*128 + cell;
    ob[(2*t)*16]     = d0;
    ob[(2*t + 1)*16] = d1;
}

// ============ ONE dispatch for all three SIFT scales ============
__global__ __launch_bounds__(256)
void sift_all(const float* __restrict__ x, float* __restrict__ s7,
              float* __restrict__ s14, float* __restrict__ s28)
{
    __shared__ float lds[4224];   // PS=32: 4*1024+128; PS=16: 4*256+128
    const int bid = blockIdx.x;
    if (bid < 784) {
        sift_block<32, 7>(x, s7, bid, lds);
    } else if (bid < 3920) {
        sift_block<16, 14>(x, s14, bid - 784, lds);
    } else {
        sift8_block(x, s28, bid - 3920);
    }
}

// ================= conv1x1 block body (device) =================
template<int CO, int S>
__device__ __forceinline__
void conv1x1_block(const float* __restrict__ in, const float* __restrict__ w,
                   const float* __restrict__ bias, float* __restrict__ out,
                   int bid, float* wt)
{
    const int tid = threadIdx.x;
    for (int i = tid; i < 128*CO; i += 256) {
        int c = i / CO, co = i - c*CO;
        wt[i] = w[co*128 + c];       // transposed: wt[c*CO+co]
    }
    __syncthreads();
    int idx = bid*256 + tid;         // 16*(CO/4)*S threads exactly
    int s = idx % S; int r = idx / S;
    int co4 = r % (CO/4); int b = r / (CO/4);
    int co = co4*4;
    const float* ib = in + (size_t)b*128*S + s;
    float acc0 = bias[co], acc1 = bias[co+1], acc2 = bias[co+2], acc3 = bias[co+3];
    #pragma unroll 8
    for (int c = 0; c < 128; c++) {
        float v = ib[c*S];
        const float4 wv = *(const float4*)&wt[c*CO + co];
        acc0 += v*wv.x; acc1 += v*wv.y; acc2 += v*wv.z; acc3 += v*wv.w;
    }
    float* ob = out + ((size_t)b*CO + co)*S + s;
    ob[0] = acc0; ob[S] = acc1; ob[2*S] = acc2; ob[3*S] = acc3;
}

// ================= L1 convT block body (device; CIN=128->32, 7->14, GN(8)) =================
__device__ __forceinline__
void convt_l1_block(const float* __restrict__ in0, const float* __restrict__ w,
                    const float* __restrict__ bias,
                    float* __restrict__ out, float2* __restrict__ pst_out,
                    int by, float* lds)
{
    constexpr int CIN = 128, COUT = 32, HIN = 7, NCH = 4, NT = 256;
    constexpr int H0 = 14, SP = 196, HIN2 = 49;
    constexpr int NR = 9, WIN = 9, TILE = CIN*NR*WIN;      // 10368
    constexpr int WSTRIDE = CIN*NCH*4 + 4;                 // 2052

    float* tile  = lds;                  // 10368
    float* wl2   = tile + TILE;          // 8208
    float* wpart = wl2 + 4*WSTRIDE;      // 8

    const int tid = threadIdx.x;
    const int b  = by >> 3;
    const int cb = by & 7;
    const int c0 = cb*NCH;

    // coalesced weight staging: iterate source-linear, scatter to parity layout
    for (int idx = tid; idx < CIN*NCH*16; idx += NT) {
        int tap = idx & 15;
        int t2 = idx >> 4;
        int j = t2 % NCH;
        int ci = t2 / NCH;
        int dy = tap >> 2, dx = tap & 3;
        int pq = (dy & 1)*2 + (dx & 1);
        int k  = (dy >> 1)*2 + (dx >> 1);
        wl2[pq*WSTRIDE + (ci*NCH + j)*4 + k] = w[(ci*COUT + c0 + j)*16 + tap];
    }
    const float* i0 = in0 + (size_t)b*CIN*HIN2;
    for (int idx = tid; idx < TILE; idx += NT) {
        int c = idx % WIN;
        int t2 = idx / WIN;
        int r = t2 % NR;
        int ci = t2 / NR;
        int iy = r - 1, ix = c - 1;
        float v = 0.f;
        if (iy >= 0 && iy < HIN && ix >= 0 && ix < HIN)
            v = i0[ci*HIN2 + iy*HIN + ix];
        tile[idx] = v;
    }
    __syncthreads();

    float acc[NCH];
    #pragma unroll
    for (int j = 0; j < NCH; j++) acc[j] = 0.f;

    const bool active = tid < SP;
    if (active) {
        int oy = tid / H0, ox = tid % H0;
        int pA = (oy+1)&1, qA = (ox+1)&1;
        int iyA = (oy+1-pA)>>1, ixA = (ox+1-qA)>>1;
        int toff = (iyA+1)*WIN + (ixA+1);
        const float* wbase = wl2 + (pA*2+qA)*WSTRIDE;

        #pragma unroll
        for (int j = 0; j < NCH; j++) acc[j] = bias[c0 + j];

        #pragma unroll 4
        for (int ci = 0; ci < CIN; ci++) {
            const float* tp = tile + ci*(NR*WIN) + toff;
            float l0 = tp[0];
            float l1 = tp[-1];
            float l2 = tp[-WIN];
            float l3 = tp[-WIN-1];
            const float* wr = wbase + ci*NCH*4;
            #pragma unroll
            for (int j = 0; j < NCH; j++) {
                const float4 wv = *(const float4*)(wr + j*4);
                acc[j] += l0*wv.x + l1*wv.y + l2*wv.z + l3*wv.w;
            }
        }
        float* ob = out + ((size_t)b*COUT + c0)*SP + tid;
        #pragma unroll
        for (int j = 0; j < NCH; j++) ob[j*SP] = acc[j];
    }

    const int wv = tid >> 6;
    const int ln = tid & 63;
    float ps = 0.f, pq2 = 0.f;
    #pragma unroll
    for (int j = 0; j < NCH; j++) {
        float v = active ? acc[j] : 0.f;
        ps += v; pq2 += v*v;
    }
    #pragma unroll
    for (int off = 32; off > 0; off >>= 1) {
        ps  += __shfl_down(ps,  off);
        pq2 += __shfl_down(pq2, off);
    }
    if (ln == 0) { wpart[wv*2] = ps; wpart[wv*2+1] = pq2; }
    __syncthreads();
    if (tid == 0) {
        float s0 = wpart[0]+wpart[2]+wpart[4]+wpart[6];
        float s1 = wpart[1]+wpart[3]+wpart[5]+wpart[7];
        pst_out[(size_t)b*8 + cb] = make_float2(s0, s1);
    }
}

// ============ ONE dispatch: both skip conv1x1s + L1 convT (independent) ============
__global__ __launch_bounds__(256)
void skip_l1(const float* __restrict__ s14, const float* __restrict__ s28,
             const float* __restrict__ s1w, const float* __restrict__ s1b,
             const float* __restrict__ s2w, const float* __restrict__ s2b,
             const float* __restrict__ s7,  const float* __restrict__ d1w,
             const float* __restrict__ d1b,
             float* __restrict__ sk1, float* __restrict__ sk2,
             float* __restrict__ h1, float2* __restrict__ pst1)
{
    __shared__ float lds[18584];   // max(conv1x1 4096, L1 10368+8208+8)
    const int bid = blockIdx.x;
    if (bid < 98)       conv1x1_block<32, 196>(s14, s1w, s1b, sk1, bid, lds);
    else if (bid < 294) conv1x1_block<16, 784>(s28, s2w, s2b, sk2, bid - 98, lds);
    else                convt_l1_block(s7, d1w, d1b, h1, pst1, bid - 294, lds);
}

// ====== ConvTranspose2d(k4,s2,p1) via LDS tile [+GN-on-read] -> partial GN stats ======
template<int CIN0, int CIN1, int COUT, int G, int HIN, int NCH, int RT, int NT,
         bool FUSE, int GIN, int NGIN, int NBLK_IN, int NBLK_OUT>
__global__ __launch_bounds__(NT)
void convt_tiled(const float* __restrict__ in0, const float* __restrict__ in1,
                 const float* __restrict__ w, const float* __restrict__ bias,
                 const float2* __restrict__ pst_in,
                 const float* __restrict__ gnw, const float* __restrict__ gnb,
                 float* __restrict__ out, float2* __restrict__ pst_out)
{
    constexpr int CIN = CIN0 + CIN1;
    constexpr int CG = COUT / G;
    constexpr int NGRP = NCH / CG;
    constexpr int CB = COUT / NCH;
    constexpr int H0 = 2*HIN;
    constexpr int SP = H0*H0;
    constexpr int HIN2 = HIN*HIN;
    constexpr int NR = RT/2 + 2;
    constexpr int WIN = HIN + 2;
    constexpr int TILE = CIN*NR*WIN;
    constexpr int WSTRIDE = CIN*NCH*4 + 4;
    constexpr int NPOS = RT*H0;
    constexpr int NWAVE = NT/64;

    __shared__ float tile[TILE];
    __shared__ float wl2[4*WSTRIDE];
    __shared__ float a_s[CIN0];
    __shared__ float b_s[CIN0];
    __shared__ float wpart[NWAVE][NGRP][2];

    const int tid = threadIdx.x;
    const int by = blockIdx.y;
    const int bx = blockIdx.x;
    const int b  = by / CB;
    const int cb = by - b*CB;
    const int c0 = cb*NCH;
    const int g0 = c0 / CG;
    const int r0 = bx * RT;
    const int row0 = r0/2 - 1;

    if constexpr (FUSE) {
        if (tid < CIN0) {
            int gi = tid / (CIN0/GIN);
            float s0 = 0.f, s1 = 0.f;
            for (int k = 0; k < NBLK_IN; k++) {
                float2 p = pst_in[((size_t)b*GIN + gi)*NBLK_IN + k];
                s0 += p.x; s1 += p.y;
            }
            float mean = s0 * (1.f/NGIN);
            float var  = s1 * (1.f/NGIN) - mean*mean;
            float inv  = rsqrtf(var + 1e-5f);
            float a = inv * gnw[tid];
            a_s[tid] = a;
            b_s[tid] = gnb[tid] - mean*a;
        }
        __syncthreads();
    }

    // coalesced weight staging
    for (int idx = tid; idx < CIN*NCH*16; idx += NT) {
        int tap = idx & 15;
        int t2 = idx >> 4;
        int j = t2 % NCH;
        int ci = t2 / NCH;
        int dy = tap >> 2, dx = tap & 3;
        int pq = (dy & 1)*2 + (dx & 1);
        int k  = (dy >> 1)*2 + (dx >> 1);
        wl2[pq*WSTRIDE + (ci*NCH + j)*4 + k] = w[(ci*COUT + c0 + j)*16 + tap];
    }

    const float* i0 = in0 + (size_t)b*CIN0*HIN2;
    for (int idx = tid; idx < TILE; idx += NT) {
        int c = idx % WIN;
        int t2 = idx / WIN;
        int r = t2 % NR;
        int ci = t2 / NR;
        int iy = row0 + r, ix = c - 1;
        float v = 0.f;
        if (iy >= 0 && iy < HIN && ix >= 0 && ix < HIN) {
            if (CIN1 == 0 || ci < CIN0) {
                v = i0[ci*HIN2 + iy*HIN + ix];
                if constexpr (FUSE) v = fmaxf(v*a_s[ci] + b_s[ci], 0.f);
            } else {
                v = in1[((size_t)b*CIN1 + (ci-CIN0))*HIN2 + iy*HIN + ix];
            }
        }
        tile[idx] = v;
    }
    __syncthreads();

    float acc[NCH];
    #pragma unroll
    for (int j = 0; j < NCH; j++) acc[j] = 0.f;

    const bool active = tid < NPOS;
    if (active) {
        int oy = r0 + tid / H0, ox = tid % H0;
        int pA = (oy+1)&1, qA = (ox+1)&1;
        int iyA = (oy+1-pA)>>1, ixA = (ox+1-qA)>>1;
        int rA = iyA - row0;
        int cA = ixA + 1;
        int toff = rA*WIN + cA;
        const float* wbase = wl2 + (pA*2+qA)*WSTRIDE;

        #pragma unroll
        for (int j = 0; j < NCH; j++) acc[j] = bias[c0 + j];

        #pragma unroll 4
        for (int ci = 0; ci < CIN; ci++) {
            const float* tp = tile + ci*(NR*WIN) + toff;
            float l0 = tp[0];
            float l1 = tp[-1];
            float l2 = tp[-WIN];
            float l3 = tp[-WIN-1];
            const float* wr = wbase + ci*NCH*4;
            #pragma unroll
            for (int j = 0; j < NCH; j++) {
                const float4 wv = *(const float4*)(wr + j*4);
                acc[j] += l0*wv.x + l1*wv.y + l2*wv.z + l3*wv.w;
            }
        }
        float* ob = out + ((size_t)b*COUT + c0)*SP + r0*H0 + tid;
        #pragma unroll
        for (int j = 0; j < NCH; j++) ob[j*SP] = acc[j];
    }

    const int wv = tid >> 6;
    const int ln = tid & 63;
    #pragma unroll
    for (int grp = 0; grp < NGRP; grp++) {
        float ps = 0.f, pq2 = 0.f;
        #pragma unroll
        for (int j = 0; j < CG; j++) {
            float v = active ? acc[grp*CG + j] : 0.f;
            ps += v; pq2 += v*v;
        }
        #pragma unroll
        for (int off = 32; off > 0; off >>= 1) {
            ps  += __shfl_down(ps,  off);
            pq2 += __shfl_down(pq2, off);
        }
        if (ln == 0) { wpart[wv][grp][0] = ps; wpart[wv][grp][1] = pq2; }
    }
    __syncthreads();
    if (tid < NGRP) {
        float s0 = 0.f, s1 = 0.f;
        #pragma unroll
        for (int w2 = 0; w2 < NWAVE; w2++) { s0 += wpart[w2][tid][0]; s1 += wpart[w2][tid][1]; }
        pst_out[((size_t)b*G + g0 + tid)*NBLK_OUT + bx] = make_float2(s0, s1);
    }
}

// ====== FUSED: final ConvTranspose2d(4->2, GN-on-read) + joint bilateral + tanh ======
__global__ __launch_bounds__(256)
void final_bilateral(const float* __restrict__ h4, const float* __restrict__ fw,
                     const float* __restrict__ fb, const float2* __restrict__ pst_in,
                     const float* __restrict__ gnw, const float* __restrict__ gnb,
                     const float* __restrict__ x, float* __restrict__ out)
{
    const float g[5] = {0.1200783f, 0.2338817f, 0.2920800f, 0.2338817f, 0.1200783f};
    __shared__ float xs[400], p0s[400], p1s[400];
    __shared__ float wl2[128];
    __shared__ float a_s[4], b_s[4], bl[2], mv[2];

    const int tid = threadIdx.x;
    const int b = blockIdx.z;
    const int ty0 = blockIdx.y*16;
    const int tx0 = blockIdx.x*16;
    const float* xb = x + (size_t)b*50176;

    if (tid < 128) {
        int k = tid & 3;
        int t = tid >> 2;
        int co = t & 1; t >>= 1;
        int ci = t & 3;
        int pq = t >> 2;
        int pA = pq >> 1, qA = pq & 1;
        int dy = pA + 2*(k>>1), dx = qA + 2*(k&1);
        wl2[tid] = fw[(ci*2 + co)*16 + dy*4 + dx];
    }
    if (tid < 2) bl[tid] = fb[tid];
    if (tid >= 192) {
        int k0 = tid - 192;
        float s0 = 0.f, s1 = 0.f;
        if (k0 < 56) {
            float2 p = pst_in[(size_t)b*56 + k0];
            s0 = p.x; s1 = p.y;
        }
        #pragma unroll
        for (int off = 32; off > 0; off >>= 1) {
            s0 += __shfl_down(s0, off);
            s1 += __shfl_down(s1, off);
        }
        if (k0 == 0) {
            float mean = s0 * (1.f/50176.f);
            float var  = s1 * (1.f/50176.f) - mean*mean;
            mv[0] = mean;
            mv[1] = rsqrtf(var + 1e-5f);
        }
    }
    __syncthreads();
    if (tid < 4) {
        float a = mv[1] * gnw[tid];
        a_s[tid] = a;
        b_s[tid] = gnb[tid] - mv[0]*a;
    }
    __syncthreads();

    const float* ib = h4 + (size_t)b*4*12544;
    for (int idx = tid; idx < 400; idx += 256) {
        int r = idx / 20, cc = idx - r*20;
        int oy = ty0 - 2 + r;  oy = oy < 0 ? -oy : (oy > 223 ? 446 - oy : oy);
        int ox = tx0 - 2 + cc; ox = ox < 0 ? -ox : (ox > 223 ? 446 - ox : ox);
        xs[idx] = xb[oy*224 + ox];

        int pA = (oy+1)&1, iyA = (oy+1-pA)>>1, iyB = iyA-1;
        int qA = (ox+1)&1, ixA = (ox+1-qA)>>1, ixB = ixA-1;
        float mYA = (iyA < 112) ? 1.f : 0.f;
        float mYB = (iyB >= 0)  ? 1.f : 0.f;
        float mXA = (ixA < 112) ? 1.f : 0.f;
        float mXB = (ixB >= 0)  ? 1.f : 0.f;
        float m0 = mYA*mXA, m1 = mYA*mXB, m2 = mYB*mXA, m3 = mYB*mXB;
        int iyAc = min(iyA, 111), iyBc = max(iyB, 0);
        int ixAc = min(ixA, 111), ixBc = max(ixB, 0);
        int oAA = iyAc*112 + ixAc, oAB = iyAc*112 + ixBc;
        int oBA = iyBc*112 + ixAc, oBB = iyBc*112 + ixBc;
        const float* wbase = wl2 + (pA*2+qA)*32;

        float acc0 = bl[0], acc1 = bl[1];
        #pragma unroll
        for (int ci = 0; ci < 4; ci++) {
            const float* ip = ib + ci*12544;
            float a = a_s[ci], bb = b_s[ci];
            float l0 = fmaxf(ip[oAA]*a + bb, 0.f);
            float l1 = fmaxf(ip[oAB]*a + bb, 0.f);
            float l2 = fmaxf(ip[oBA]*a + bb, 0.f);
            float l3 = fmaxf(ip[oBB]*a + bb, 0.f);
            float t0 = l0*m0, t1 = l1*m1, t2 = l2*m2, t3 = l3*m3;
            const float4 w0 = *(const float4*)(wbase + ci*8);
            const float4 w1 = *(const float4*)(wbase + ci*8 + 4);
            acc0 += t0*w0.x + t1*w0.y + t2*w0.z + t3*w0.w;
            acc1 += t0*w1.x + t1*w1.y + t2*w1.z + t3*w1.w;
        }
        p0s[idx] = acc0;
        p1s[idx] = acc1;
    }
    __syncthreads();

    int ly = tid >> 4, lx = tid & 15;
    int base = (ly+2)*20 + (lx+2);
    float center = xs[base];
    float wsum = 0.f, a0 = 0.f, a1 = 0.f;
    #pragma unroll
    for (int di = -2; di <= 2; di++){
        #pragma unroll
        for (int dj = -2; dj <= 2; dj++){
            int o = base + di*20 + dj;
            float dg = xs[o] - center;
            float wgt = g[di+2]*g[dj+2]*__expf(-200.f*dg*dg);
            wsum += wgt;
            a0 += wgt * p0s[o];
            a1 += wgt * p1s[o];
        }
    }
    float inv = 1.0f / wsum;
    int s = (ty0 + ly)*224 + (tx0 + lx);
    out[(size_t)(b*2)*50176 + s]     = tanhf(a0*inv)*0.436f;
    out[(size_t)(b*2+1)*50176 + s]   = tanhf(a1*inv)*0.615f;
}

// ======================= launch =======================
extern "C" void kernel_launch(void* const* d_in, const int* in_sizes, int n_in,
                              void* d_out, int out_size, void* d_ws, size_t ws_size,
                              hipStream_t stream) {
    (void)in_sizes; (void)n_in; (void)out_size; (void)ws_size;
    const float* x   = (const float*)d_in[0];
    const float* d1w = (const float*)d_in[1];
    const float* d1b = (const float*)d_in[2];
    const float* g1w = (const float*)d_in[3];
    const float* g1b = (const float*)d_in[4];
    const float* s1w = (const float*)d_in[5];
    const float* s1b = (const float*)d_in[6];
    const float* d2w = (const float*)d_in[7];
    const float* d2b = (const float*)d_in[8];
    const float* g2w = (const float*)d_in[9];
    const float* g2b = (const float*)d_in[10];
    const float* s2w = (const float*)d_in[11];
    const float* s2b = (const float*)d_in[12];
    const float* d3w = (const float*)d_in[13];
    const float* d3b = (const float*)d_in[14];
    const float* g3w = (const float*)d_in[15];
    const float* g3b = (const float*)d_in[16];
    const float* d4w = (const float*)d_in[17];
    const float* d4b = (const float*)d_in[18];
    const float* g4w = (const float*)d_in[19];
    const float* g4b = (const float*)d_in[20];
    const float* fw  = (const float*)d_in[21];
    const float* fb  = (const float*)d_in[22];
    float* out = (float*)d_out;

    float* ws  = (float*)d_ws;
    float* s7  = ws;                  // 16*128*49      = 100352
    float* s14 = s7  + 100352;        // 16*128*196     = 401408
    float* s28 = s14 + 401408;        // 16*128*784     = 1605632
    float* sk1 = s28 + 1605632;       // 16*32*196      = 100352
    float* sk2 = sk1 + 100352;        // 16*16*784      = 200704
    float* h1  = sk2 + 200704;        // 16*32*196      = 100352
    float* h2  = h1  + 100352;        // 16*16*784      = 200704
    float* h3  = h2  + 200704;        // 16*8*3136      = 401408
    float* h4  = h3  + 401408;        // 16*4*12544     = 802816
    float2* pst1 = (float2*)(h4 + 802816);     // 16*8  * 1  = 128 pairs
    float2* pst2 = pst1 + 128;                 // 16*4  * 7  = 448 pairs
    float2* pst3 = pst2 + 448;                 // 16*2  * 14 = 448 pairs
    float2* pst4 = pst3 + 448;                 // 16*1  * 56 = 896 pairs

    // d1: all SIFT scales (784 + 3136 + 3136 blocks)
    sift_all<<<7056, 256, 0, stream>>>(x, s7, s14, s28);

    // d2: both skip conv1x1s + L1 convT — 98+196+128 blocks
    skip_l1<<<422, 256, 0, stream>>>(s14, s28, s1w, s1b, s2w, s2b,
                                     s7, d1w, d1b, sk1, sk2, h1, pst1);

    // d3: L2 convT(64->16, 14->28), GN(4) — NT=256 (NPOS=112 active in conv)
    convt_tiled< 32,32, 16, 4, 14, 8,  4, 256, true, 8, 784, 1, 7>
        <<<dim3(7, 16*2), 256, 0, stream>>>(h1, sk1, d2w, d2b, pst1, g1w, g1b, h2, pst2);
    // d4: L3 convT(32->8, 28->56), GN(2)
    convt_tiled< 16,16,  8, 2, 28, 8,  4, 256, true, 4, 3136, 7, 14>
        <<<dim3(14, 16), 256, 0, stream>>>(h2, sk2, d3w, d3b, pst2, g2w, g2b, h3, pst3);
    // d5: L4 convT(8->4, 56->112), GN(1)
    convt_tiled<  8, 0,  4, 1, 56, 4,  2, 256, true, 2, 12544, 14, 56>
        <<<dim3(56, 16), 256, 0, stream>>>(h3, nullptr, d4w, d4b, pst3, g3w, g3b, h4, pst4);

    // d6: fused head (final convT GN-on-read + bilateral + tanh)
    final_bilateral<<<dim3(14, 14, 16), 256, 0, stream>>>(h4, fw, fb, pst4, g4w, g4b, x, out);
}